// Round 4
// baseline (1706.424 us; speedup 1.0000x reference)
//
#include <hip/hip_runtime.h>

#define N_NODES 100000
#define E_EDGES 600000
#define HID 128

typedef __attribute__((ext_vector_type(8))) short short8v;
typedef __attribute__((ext_vector_type(4))) float f32x4;

__device__ __forceinline__ unsigned short bf16rne(float x) {
  unsigned u = __float_as_uint(x);
  return (unsigned short)((u + 0x7FFFu + ((u >> 16) & 1u)) >> 16);
}

// ------------- last-edge (last-write-wins) + dst-degree histogram -------------
__global__ void k_last(const int* __restrict__ ei, int* __restrict__ last_src,
                       int* __restrict__ last_dst, int* __restrict__ deg, int E) {
  int e = blockIdx.x * blockDim.x + threadIdx.x;
  if (e >= E) return;
  int s = ei[e], d = ei[E + e];
  atomicMax(&last_src[s], e);
  atomicMax(&last_dst[d], e);
  atomicAdd(&deg[d], 1);
}

// ------------- 2-level exclusive scan over deg (CSR row offsets) -------------
__global__ __launch_bounds__(256) void k_scan1(const int* __restrict__ deg,
                                               int* __restrict__ excl,
                                               int* __restrict__ bsum, int n) {
  __shared__ int sh[256];
  int b = blockIdx.x, t = threadIdx.x;
  int i0 = b * 1024 + t * 4;
  int v0 = (i0 + 0 < n) ? deg[i0 + 0] : 0;
  int v1 = (i0 + 1 < n) ? deg[i0 + 1] : 0;
  int v2 = (i0 + 2 < n) ? deg[i0 + 2] : 0;
  int v3 = (i0 + 3 < n) ? deg[i0 + 3] : 0;
  int tsum = v0 + v1 + v2 + v3;
  sh[t] = tsum;
  __syncthreads();
  for (int off = 1; off < 256; off <<= 1) {
    int add = (t >= off) ? sh[t - off] : 0;
    __syncthreads();
    sh[t] += add;
    __syncthreads();
  }
  int ex = sh[t] - tsum;
  if (i0 + 0 < n) excl[i0 + 0] = ex;
  if (i0 + 1 < n) excl[i0 + 1] = ex + v0;
  if (i0 + 2 < n) excl[i0 + 2] = ex + v0 + v1;
  if (i0 + 3 < n) excl[i0 + 3] = ex + v0 + v1 + v2;
  if (t == 255) bsum[b] = sh[255];
}

__global__ void k_scan2(const int* __restrict__ bsum, int* __restrict__ boff, int nb) {
  __shared__ int sh[128];
  int t = threadIdx.x;
  int v = (t < nb) ? bsum[t] : 0;
  sh[t] = v;
  __syncthreads();
  for (int off = 1; off < 128; off <<= 1) {
    int add = (t >= off) ? sh[t - off] : 0;
    __syncthreads();
    sh[t] += add;
    __syncthreads();
  }
  if (t < nb) boff[t] = sh[t] - v;
}

// ------------- scatter edges into dst buckets: (src, attr) pairs -------------
__global__ void k_scatter(const int* __restrict__ ei, const float* __restrict__ ea,
                          const int* __restrict__ excl, const int* __restrict__ boff,
                          int* __restrict__ cnt, int* __restrict__ swv,
                          float* __restrict__ awv, int E) {
  int e = blockIdx.x * blockDim.x + threadIdx.x;
  if (e >= E) return;
  int d = ei[E + e];
  int p = excl[d] + boff[d >> 10] + atomicAdd(&cnt[d], 1);
  swv[p] = ei[e];
  awv[p] = ea[e];
}

// ---------------- piecewise-linear edge-encoder table ----------------
__global__ void k_table(const float* __restrict__ W1g, const float* __restrict__ b1g,
                        const float* __restrict__ W2g, const float* __restrict__ b2g,
                        float* __restrict__ tabA, float* __restrict__ tabB,
                        float* __restrict__ tsort) {
  __shared__ float w1[128], b1[128], key[128];
  __shared__ int idx[128];
  __shared__ float w2[128][128];
  const int t = threadIdx.x;  // 128 threads
  w1[t] = W1g[t];
  b1[t] = b1g[t];
  for (int k = 0; k < 128; ++k) w2[k][t] = W2g[k * 128 + t];
  __syncthreads();
  float s0 = w1[t];
  key[t] = (s0 != 0.0f) ? (-b1[t] / s0) : __builtin_inff();
  idx[t] = t;
  for (int size = 2; size <= 128; size <<= 1) {
    for (int stride = size >> 1; stride > 0; stride >>= 1) {
      __syncthreads();
      int p = t ^ stride;
      if (p > t) {
        bool up = ((t & size) == 0);
        float k1 = key[t], k2 = key[p];
        if (up == (k1 > k2)) {
          int i1 = idx[t], i2 = idx[p];
          key[t] = k2; key[p] = k1; idx[t] = i2; idx[p] = i1;
        }
      }
    }
  }
  __syncthreads();
  tsort[t] = key[t];
  float A = 0.0f, B = b2g[t];
  for (int k = 0; k < 128; ++k) {
    float s = w1[k], bb = b1[k], w = w2[k][t];
    if (s < 0.0f) { A = fmaf(s, w, A); B = fmaf(bb, w, B); }
    else if (s == 0.0f && bb > 0.0f) { B = fmaf(bb, w, B); }
  }
  tabA[t] = A;
  tabB[t] = B;
  for (int i = 0; i < 128; ++i) {
    float kv = key[i];
    int kk = idx[i];
    if (kv < __builtin_inff()) {
      float s = w1[kk], bb = b1[kk], w = w2[kk][t];
      if (s > 0.0f) { A = fmaf(s, w, A); B = fmaf(bb, w, B); }
      else { A = fmaf(-s, w, A); B = fmaf(-bb, w, B); }
    }
    tabA[(i + 1) * 128 + t] = A;
    tabB[(i + 1) * 128 + t] = B;
  }
}

// ------------- per-edge interval index (removes search from k_agg) -------------
__global__ __launch_bounds__(256) void k_pos(const float* __restrict__ awv,
                                             const float* __restrict__ tsort,
                                             unsigned char* __restrict__ posb, int E) {
  __shared__ float ts[128];
  if (threadIdx.x < 128) ts[threadIdx.x] = tsort[threadIdx.x];
  __syncthreads();
  int i = blockIdx.x * blockDim.x + threadIdx.x;
  if (i >= E) return;
  float a = awv[i];
  int pos = 0;
#pragma unroll
  for (int st = 64; st > 0; st >>= 1)
    if (pos + st <= 128 && ts[pos + st - 1] < a) pos += st;
  posb[i] = (unsigned char)pos;
}

// ------- per-node gather-aggregate: zin[n] = (1+eps)*h[n] + sum relu(...) -------
__global__ __launch_bounds__(256) void k_agg(
    const float* __restrict__ h, const int* __restrict__ swv,
    const float* __restrict__ awv, const unsigned char* __restrict__ posb,
    const int* __restrict__ excl, const int* __restrict__ boff,
    const float* __restrict__ tabA, const float* __restrict__ tabB,
    const float* __restrict__ epsP, float* __restrict__ zin, int N, int E) {
  int w = (int)((blockIdx.x * 256 + threadIdx.x) >> 6);  // one wave per node
  if (w >= N) return;
  int lane = threadIdx.x & 63;
  int start = excl[w] + boff[w >> 10];
  int end = (w + 1 < N) ? (excl[w + 1] + boff[(w + 1) >> 10]) : E;
  int j = lane * 2;
  float a0 = 0.0f, a1 = 0.0f, c0 = 0.0f, c1 = 0.0f;
  int i = start;
  for (; i + 2 <= end; i += 2) {
    int s0 = swv[i], s1 = swv[i + 1];
    float aa = awv[i], ab = awv[i + 1];
    int p0 = posb[i], p1 = posb[i + 1];
    float2 h0 = *(const float2*)(h + (size_t)s0 * HID + j);
    float2 A0 = *(const float2*)(tabA + (size_t)p0 * HID + j);
    float2 B0 = *(const float2*)(tabB + (size_t)p0 * HID + j);
    float2 h1 = *(const float2*)(h + (size_t)s1 * HID + j);
    float2 A1 = *(const float2*)(tabA + (size_t)p1 * HID + j);
    float2 B1 = *(const float2*)(tabB + (size_t)p1 * HID + j);
    a0 += fmaxf(h0.x + fmaf(A0.x, aa, B0.x), 0.0f);
    a1 += fmaxf(h0.y + fmaf(A0.y, aa, B0.y), 0.0f);
    c0 += fmaxf(h1.x + fmaf(A1.x, ab, B1.x), 0.0f);
    c1 += fmaxf(h1.y + fmaf(A1.y, ab, B1.y), 0.0f);
  }
  if (i < end) {
    int s0 = swv[i];
    float aa = awv[i];
    int p0 = posb[i];
    float2 h0 = *(const float2*)(h + (size_t)s0 * HID + j);
    float2 A0 = *(const float2*)(tabA + (size_t)p0 * HID + j);
    float2 B0 = *(const float2*)(tabB + (size_t)p0 * HID + j);
    a0 += fmaxf(h0.x + fmaf(A0.x, aa, B0.x), 0.0f);
    a1 += fmaxf(h0.y + fmaf(A0.y, aa, B0.y), 0.0f);
  }
  a0 += c0;
  a1 += c1;
  float ep1 = 1.0f + *epsP;
  float2 hn = *(const float2*)(h + (size_t)w * HID + j);
  float2 o;
  o.x = fmaf(ep1, hn.x, a0);
  o.y = fmaf(ep1, hn.y, a1);
  *(float2*)(zin + (size_t)w * HID + j) = o;
}

// ------------- weight pack into B-fragment layout (bf16) -------------
// frag f = mt*KS + ks; per lane: col = mt*16 + (lane&15), k = ks*32+(lane>>4)*8+i
__device__ __forceinline__ void pack_one(const float* __restrict__ W, int K, int M,
                                         int t, unsigned short* __restrict__ out) {
  int lane = t & 63, f = t >> 6;
  int KS = K >> 5;
  int mt = f / KS, ks = f - mt * KS;
  int col = mt * 16 + (lane & 15);
  int kb = ks * 32 + ((lane >> 4) * 8);
  unsigned r0 = 0, r1 = 0, r2 = 0, r3 = 0;
  r0 = bf16rne(W[(size_t)(kb + 0) * M + col]) | ((unsigned)bf16rne(W[(size_t)(kb + 1) * M + col]) << 16);
  r1 = bf16rne(W[(size_t)(kb + 2) * M + col]) | ((unsigned)bf16rne(W[(size_t)(kb + 3) * M + col]) << 16);
  r2 = bf16rne(W[(size_t)(kb + 4) * M + col]) | ((unsigned)bf16rne(W[(size_t)(kb + 5) * M + col]) << 16);
  r3 = bf16rne(W[(size_t)(kb + 6) * M + col]) | ((unsigned)bf16rne(W[(size_t)(kb + 7) * M + col]) << 16);
  uint4 v = make_uint4(r0, r1, r2, r3);
  *(uint4*)(out + ((size_t)f * 64 + lane) * 8) = v;
}

__global__ __launch_bounds__(256) void k_pack(
    const float* __restrict__ lin_W, const float* __restrict__ m1_W,
    const float* __restrict__ m2_W, unsigned short* __restrict__ pk_lin,
    unsigned short* __restrict__ pk_m1, unsigned short* __restrict__ pk_m2) {
  int t = blockIdx.x * 256 + threadIdx.x;
  if (t < 2048) {
    pack_one(lin_W, 128, 128, t, pk_lin);
  } else if (t < 10240) {
    int u = t - 2048;
    int l = u >> 12;
    pack_one(m1_W + (size_t)l * 128 * 256, 128, 256, u & 4095, pk_m1 + (size_t)l * 32768);
  } else if (t < 18432) {
    int u = t - 10240;
    int l = u >> 12;
    pack_one(m2_W + (size_t)l * 256 * 128, 256, 128, u & 4095, pk_m2 + (size_t)l * 32768);
  }
}

// ---------------- MFMA skinny GEMM: out = pre(in) @ W + bias ----------------
// Wave = 16 rows x full M. A frags built in regs from fp32; B from packed bf16.
// MODE 0: epilogue agg_edge(last_dst/last_src, enc)
// MODE 1: store z2 + BN column partial sums
// MODE 2: pre-op relu(in*scale+shift); optional relu on store
template <int K, int M, int MODE, bool RELU_OUT>
__global__ __launch_bounds__(256) void k_mgemm(
    const float* __restrict__ in0, const unsigned short* __restrict__ pkW,
    const float* __restrict__ bias, float* __restrict__ out,
    const float* __restrict__ pre_a, const float* __restrict__ pre_b,
    float* __restrict__ colsum, float* __restrict__ colsumsq,
    const int* __restrict__ last_dst, const int* __restrict__ last_src,
    const float* __restrict__ ea, const float* __restrict__ encW,
    const float* __restrict__ encb) {
  constexpr int KS = K / 32, MT = M / 16;
  const int t = threadIdx.x;
  const int w = t >> 6, lane = t & 63;
  const int row0 = blockIdx.x * 64 + w * 16;
  const int arow = row0 + (lane & 15);
  const int rg = arow < N_NODES ? arow : N_NODES - 1;
  const int kb = (lane >> 4) * 8;

  short8v afrag[KS];
#pragma unroll
  for (int ks = 0; ks < KS; ++ks) {
    const int k0 = ks * 32 + kb;
    float4 v0 = *(const float4*)(in0 + (size_t)rg * K + k0);
    float4 v1 = *(const float4*)(in0 + (size_t)rg * K + k0 + 4);
    if (MODE == 2) {
      float4 sa0 = *(const float4*)(pre_a + k0);
      float4 sa1 = *(const float4*)(pre_a + k0 + 4);
      float4 sb0 = *(const float4*)(pre_b + k0);
      float4 sb1 = *(const float4*)(pre_b + k0 + 4);
      v0.x = fmaxf(fmaf(v0.x, sa0.x, sb0.x), 0.0f);
      v0.y = fmaxf(fmaf(v0.y, sa0.y, sb0.y), 0.0f);
      v0.z = fmaxf(fmaf(v0.z, sa0.z, sb0.z), 0.0f);
      v0.w = fmaxf(fmaf(v0.w, sa0.w, sb0.w), 0.0f);
      v1.x = fmaxf(fmaf(v1.x, sa1.x, sb1.x), 0.0f);
      v1.y = fmaxf(fmaf(v1.y, sa1.y, sb1.y), 0.0f);
      v1.z = fmaxf(fmaf(v1.z, sa1.z, sb1.z), 0.0f);
      v1.w = fmaxf(fmaf(v1.w, sa1.w, sb1.w), 0.0f);
    }
    short8v a;
    a[0] = (short)bf16rne(v0.x); a[1] = (short)bf16rne(v0.y);
    a[2] = (short)bf16rne(v0.z); a[3] = (short)bf16rne(v0.w);
    a[4] = (short)bf16rne(v1.x); a[5] = (short)bf16rne(v1.y);
    a[6] = (short)bf16rne(v1.z); a[7] = (short)bf16rne(v1.w);
    afrag[ks] = a;
  }

  f32x4 acc[MT];
#pragma unroll
  for (int mt = 0; mt < MT; ++mt) acc[mt] = (f32x4){0.f, 0.f, 0.f, 0.f};
#pragma unroll
  for (int mt = 0; mt < MT; ++mt) {
#pragma unroll
    for (int ks = 0; ks < KS; ++ks) {
      short8v bfrag = *(const short8v*)(pkW + ((size_t)(mt * KS + ks) * 64 + lane) * 8);
      acc[mt] = __builtin_amdgcn_mfma_f32_16x16x32_bf16(afrag[ks], bfrag, acc[mt], 0, 0, 0);
    }
  }

  // epilogue: C/D layout col = lane&15, row = (lane>>4)*4 + reg
  const int colb = lane & 15;
  const int rbase = row0 + (lane >> 4) * 4;
#pragma unroll
  for (int mt = 0; mt < MT; ++mt) {
    const int col = mt * 16 + colb;
    const float b = bias[col];
    if (MODE == 1) {
      float s1 = 0.0f, s2 = 0.0f;
#pragma unroll
      for (int r = 0; r < 4; ++r) {
        int R = rbase + r;
        if (R < N_NODES) {
          float v = acc[mt][r] + b;
          out[(size_t)R * M + col] = v;
          s1 += v;
          s2 = fmaf(v, v, s2);
        }
      }
      s1 += __shfl_xor(s1, 16);
      s1 += __shfl_xor(s1, 32);
      s2 += __shfl_xor(s2, 16);
      s2 += __shfl_xor(s2, 32);
      if (lane < 16) {
        atomicAdd(&colsum[col], s1);
        atomicAdd(&colsumsq[col], s2);
      }
    } else if (MODE == 2) {
#pragma unroll
      for (int r = 0; r < 4; ++r) {
        int R = rbase + r;
        if (R < N_NODES) {
          float v = acc[mt][r] + b;
          if (RELU_OUT) v = fmaxf(v, 0.0f);
          out[(size_t)R * M + col] = v;
        }
      }
    } else {
      const float ew = encW[col], eb = encb[col];
#pragma unroll
      for (int r = 0; r < 4; ++r) {
        int R = rbase + r;
        if (R < N_NODES) {
          float v = acc[mt][r] + b;
          int ld = last_dst[R];
          int ls = last_src[R];
          int e = (ld >= 0) ? ld : ls;  // dst assignment overwrites src assignment
          if (e >= 0) v = fmaxf(v + fmaf(ea[e], ew, eb), 0.0f);
          out[(size_t)R * M + col] = v;
        }
      }
    }
  }
}

// ---------------- BN finalize: scale/shift per column ----------------
__global__ void k_bnfin(const float* __restrict__ colsum, const float* __restrict__ colsumsq,
                        const float* __restrict__ g, const float* __restrict__ bb,
                        float* __restrict__ scale, float* __restrict__ shift) {
  int j = threadIdx.x;  // 256
  const float inv = 1.0f / (float)N_NODES;
  float mu = colsum[j] * inv;
  float var = colsumsq[j] * inv - mu * mu;
  float sc = g[j] * rsqrtf(var + 1e-5f);
  scale[j] = sc;
  shift[j] = fmaf(-mu, sc, bb[j]);
}

extern "C" void kernel_launch(void* const* d_in, const int* in_sizes, int n_in,
                              void* d_out, int out_size, void* d_ws, size_t ws_size,
                              hipStream_t stream) {
  const float* x     = (const float*)d_in[0];
  const int*   ei    = (const int*)d_in[1];
  const float* ea    = (const float*)d_in[2];
  const float* lin_W = (const float*)d_in[3];
  const float* lin_b = (const float*)d_in[4];
  const float* enc_W = (const float*)d_in[5];
  const float* enc_b = (const float*)d_in[6];
  const float* eps   = (const float*)d_in[7];
  const float* e1_W  = (const float*)d_in[8];
  const float* e1_b  = (const float*)d_in[9];
  const float* e2_W  = (const float*)d_in[10];
  const float* e2_b  = (const float*)d_in[11];
  const float* m1_W  = (const float*)d_in[12];
  const float* m1_b  = (const float*)d_in[13];
  const float* bn_g  = (const float*)d_in[14];
  const float* bn_b  = (const float*)d_in[15];
  const float* m2_W  = (const float*)d_in[16];
  const float* m2_b  = (const float*)d_in[17];
  float* hbuf = (float*)d_out;  // h lives in d_out; final GEMM2 overwrites it

  float* ws = (float*)d_ws;
  size_t o = 0;
  float* zin = ws;                 o += (size_t)N_NODES * 128;
  float* z2 = ws + o;              o += (size_t)N_NODES * 256;
  int* last_dst = (int*)(ws + o);  o += N_NODES;
  int* last_src = (int*)(ws + o);  o += N_NODES;
  int* deg = (int*)(ws + o);       o += N_NODES;
  int* cnt = (int*)(ws + o);       o += N_NODES;
  int* excl = (int*)(ws + o);      o += N_NODES;
  int* bsum = (int*)(ws + o);      o += 128;
  int* boff = (int*)(ws + o);      o += 128;
  int* swv = (int*)(ws + o);       o += E_EDGES;
  float* awv = ws + o;             o += E_EDGES;
  unsigned char* posb = (unsigned char*)(ws + o); o += (E_EDGES + 3) / 4 + 4;
  float* tabA = ws + o;            o += 129 * 128;
  float* tabB = ws + o;            o += 129 * 128;
  float* tsort = ws + o;           o += 128;
  float* colsum = ws + o;          o += 256;
  float* colsumsq = ws + o;        o += 256;
  float* scale = ws + o;           o += 256;
  float* shift = ws + o;           o += 256;
  unsigned short* pk_lin = (unsigned short*)(ws + o); o += 8192;   // 16384 bf16
  unsigned short* pk_m1  = (unsigned short*)(ws + o); o += 32768;  // 2 x 32768 bf16
  unsigned short* pk_m2  = (unsigned short*)(ws + o); o += 32768;  // 2 x 32768 bf16
  if (ws_size < o * sizeof(float)) return;

  const int NB_SCAN = (N_NODES + 1023) / 1024;  // 98
  const int NB_GEMM = (N_NODES + 63) / 64;      // 1563

  hipMemsetAsync(last_dst, 0xFF, 2 * (size_t)N_NODES * sizeof(int), stream);
  hipMemsetAsync(deg, 0, 2 * (size_t)N_NODES * sizeof(int), stream);  // deg + cnt
  k_last<<<(E_EDGES + 255) / 256, 256, 0, stream>>>(ei, last_src, last_dst, deg, E_EDGES);
  k_scan1<<<NB_SCAN, 256, 0, stream>>>(deg, excl, bsum, N_NODES);
  k_scan2<<<1, 128, 0, stream>>>(bsum, boff, NB_SCAN);
  k_scatter<<<(E_EDGES + 255) / 256, 256, 0, stream>>>(ei, ea, excl, boff, cnt, swv, awv, E_EDGES);
  k_pack<<<72, 256, 0, stream>>>(lin_W, m1_W, m2_W, pk_lin, pk_m1, pk_m2);

  // h = x @ lin_W + lin_b, then agg_edge epilogue
  k_mgemm<128, 128, 0, false><<<NB_GEMM, 256, 0, stream>>>(
      x, pk_lin, lin_b, hbuf, nullptr, nullptr, nullptr, nullptr,
      last_dst, last_src, ea, enc_W, enc_b);

  for (int l = 0; l < 2; ++l) {
    k_table<<<1, 128, 0, stream>>>(e1_W + l * 128, e1_b + l * 128,
                                   e2_W + l * 128 * 128, e2_b + l * 128,
                                   tabA, tabB, tsort);
    k_pos<<<(E_EDGES + 255) / 256, 256, 0, stream>>>(awv, tsort, posb, E_EDGES);
    k_agg<<<(N_NODES * 64 + 255) / 256, 256, 0, stream>>>(
        hbuf, swv, awv, posb, excl, boff, tabA, tabB, eps + l, zin, N_NODES, E_EDGES);
    hipMemsetAsync(colsum, 0, 512 * sizeof(float), stream);
    k_mgemm<128, 256, 1, false><<<NB_GEMM, 256, 0, stream>>>(
        zin, pk_m1 + (size_t)l * 32768, m1_b + l * 256, z2, nullptr, nullptr,
        colsum, colsumsq, nullptr, nullptr, nullptr, nullptr, nullptr);
    k_bnfin<<<1, 256, 0, stream>>>(colsum, colsumsq, bn_g + l * 256, bn_b + l * 256,
                                   scale, shift);
    if (l == 0) {
      k_mgemm<256, 128, 2, true><<<NB_GEMM, 256, 0, stream>>>(
          z2, pk_m2 + (size_t)l * 32768, m2_b + l * 128, hbuf, scale, shift,
          nullptr, nullptr, nullptr, nullptr, nullptr, nullptr, nullptr);
    } else {
      k_mgemm<256, 128, 2, false><<<NB_GEMM, 256, 0, stream>>>(
          z2, pk_m2 + (size_t)l * 32768, m2_b + l * 128, hbuf, scale, shift,
          nullptr, nullptr, nullptr, nullptr, nullptr, nullptr, nullptr);
    }
  }
}

// Round 5
// 1008.259 us; speedup vs baseline: 1.6924x; 1.6924x over previous
//
#include <hip/hip_runtime.h>

#define N_NODES 100000
#define E_EDGES 600000
#define HID 128

typedef __attribute__((ext_vector_type(8))) short short8v;
typedef __attribute__((ext_vector_type(4))) float f32x4;

__device__ __forceinline__ unsigned short bf16rne(float x) {
  unsigned u = __float_as_uint(x);
  return (unsigned short)((u + 0x7FFFu + ((u >> 16) & 1u)) >> 16);
}

// ------------- last-edge (last-write-wins) + dst-degree histogram -------------
__global__ void k_last(const int* __restrict__ ei, int* __restrict__ last_src,
                       int* __restrict__ last_dst, int* __restrict__ deg, int E) {
  int e = blockIdx.x * blockDim.x + threadIdx.x;
  if (e >= E) return;
  int s = ei[e], d = ei[E + e];
  atomicMax(&last_src[s], e);
  atomicMax(&last_dst[d], e);
  atomicAdd(&deg[d], 1);
}

// ------------- 2-level exclusive scan over deg (CSR row offsets) -------------
__global__ __launch_bounds__(256) void k_scan1(const int* __restrict__ deg,
                                               int* __restrict__ excl,
                                               int* __restrict__ bsum, int n) {
  __shared__ int sh[256];
  int b = blockIdx.x, t = threadIdx.x;
  int i0 = b * 1024 + t * 4;
  int v0 = (i0 + 0 < n) ? deg[i0 + 0] : 0;
  int v1 = (i0 + 1 < n) ? deg[i0 + 1] : 0;
  int v2 = (i0 + 2 < n) ? deg[i0 + 2] : 0;
  int v3 = (i0 + 3 < n) ? deg[i0 + 3] : 0;
  int tsum = v0 + v1 + v2 + v3;
  sh[t] = tsum;
  __syncthreads();
  for (int off = 1; off < 256; off <<= 1) {
    int add = (t >= off) ? sh[t - off] : 0;
    __syncthreads();
    sh[t] += add;
    __syncthreads();
  }
  int ex = sh[t] - tsum;
  if (i0 + 0 < n) excl[i0 + 0] = ex;
  if (i0 + 1 < n) excl[i0 + 1] = ex + v0;
  if (i0 + 2 < n) excl[i0 + 2] = ex + v0 + v1;
  if (i0 + 3 < n) excl[i0 + 3] = ex + v0 + v1 + v2;
  if (t == 255) bsum[b] = sh[255];
}

__global__ void k_scan2(const int* __restrict__ bsum, int* __restrict__ boff, int nb) {
  __shared__ int sh[128];
  int t = threadIdx.x;
  int v = (t < nb) ? bsum[t] : 0;
  sh[t] = v;
  __syncthreads();
  for (int off = 1; off < 128; off <<= 1) {
    int add = (t >= off) ? sh[t - off] : 0;
    __syncthreads();
    sh[t] += add;
    __syncthreads();
  }
  if (t < nb) boff[t] = sh[t] - v;
}

// ------------- scatter edges into dst buckets: (src, attr) pairs -------------
__global__ void k_scatter(const int* __restrict__ ei, const float* __restrict__ ea,
                          const int* __restrict__ excl, const int* __restrict__ boff,
                          int* __restrict__ cnt, int* __restrict__ swv,
                          float* __restrict__ awv, int E) {
  int e = blockIdx.x * blockDim.x + threadIdx.x;
  if (e >= E) return;
  int d = ei[E + e];
  int p = excl[d] + boff[d >> 10] + atomicAdd(&cnt[d], 1);
  swv[p] = ei[e];
  awv[p] = ea[e];
}

// ---------------- piecewise-linear edge-encoder table ----------------
__global__ void k_table(const float* __restrict__ W1g, const float* __restrict__ b1g,
                        const float* __restrict__ W2g, const float* __restrict__ b2g,
                        float* __restrict__ tabA, float* __restrict__ tabB,
                        float* __restrict__ tsort) {
  __shared__ float w1[128], b1[128], key[128];
  __shared__ int idx[128];
  __shared__ float w2[128][128];
  const int t = threadIdx.x;  // 128 threads
  w1[t] = W1g[t];
  b1[t] = b1g[t];
  for (int k = 0; k < 128; ++k) w2[k][t] = W2g[k * 128 + t];
  __syncthreads();
  float s0 = w1[t];
  key[t] = (s0 != 0.0f) ? (-b1[t] / s0) : __builtin_inff();
  idx[t] = t;
  for (int size = 2; size <= 128; size <<= 1) {
    for (int stride = size >> 1; stride > 0; stride >>= 1) {
      __syncthreads();
      int p = t ^ stride;
      if (p > t) {
        bool up = ((t & size) == 0);
        float k1 = key[t], k2 = key[p];
        if (up == (k1 > k2)) {
          int i1 = idx[t], i2 = idx[p];
          key[t] = k2; key[p] = k1; idx[t] = i2; idx[p] = i1;
        }
      }
    }
  }
  __syncthreads();
  tsort[t] = key[t];
  float A = 0.0f, B = b2g[t];
  for (int k = 0; k < 128; ++k) {
    float s = w1[k], bb = b1[k], w = w2[k][t];
    if (s < 0.0f) { A = fmaf(s, w, A); B = fmaf(bb, w, B); }
    else if (s == 0.0f && bb > 0.0f) { B = fmaf(bb, w, B); }
  }
  tabA[t] = A;
  tabB[t] = B;
  for (int i = 0; i < 128; ++i) {
    float kv = key[i];
    int kk = idx[i];
    if (kv < __builtin_inff()) {
      float s = w1[kk], bb = b1[kk], w = w2[kk][t];
      if (s > 0.0f) { A = fmaf(s, w, A); B = fmaf(bb, w, B); }
      else { A = fmaf(-s, w, A); B = fmaf(-bb, w, B); }
    }
    tabA[(i + 1) * 128 + t] = A;
    tabB[(i + 1) * 128 + t] = B;
  }
}

// ------------- per-edge interval index (removes search from k_agg) -------------
__global__ __launch_bounds__(256) void k_pos(const float* __restrict__ awv,
                                             const float* __restrict__ tsort,
                                             unsigned char* __restrict__ posb, int E) {
  __shared__ float ts[128];
  if (threadIdx.x < 128) ts[threadIdx.x] = tsort[threadIdx.x];
  __syncthreads();
  int i = blockIdx.x * blockDim.x + threadIdx.x;
  if (i >= E) return;
  float a = awv[i];
  int pos = 0;
#pragma unroll
  for (int st = 64; st > 0; st >>= 1)
    if (pos + st <= 128 && ts[pos + st - 1] < a) pos += st;
  posb[i] = (unsigned char)pos;
}

// ------- per-node gather-aggregate: zin[n] = (1+eps)*h[n] + sum relu(...) -------
__global__ __launch_bounds__(256) void k_agg(
    const float* __restrict__ h, const int* __restrict__ swv,
    const float* __restrict__ awv, const unsigned char* __restrict__ posb,
    const int* __restrict__ excl, const int* __restrict__ boff,
    const float* __restrict__ tabA, const float* __restrict__ tabB,
    const float* __restrict__ epsP, float* __restrict__ zin, int N, int E) {
  int w = (int)((blockIdx.x * 256 + threadIdx.x) >> 6);  // one wave per node
  if (w >= N) return;
  int lane = threadIdx.x & 63;
  int start = excl[w] + boff[w >> 10];
  int end = (w + 1 < N) ? (excl[w + 1] + boff[(w + 1) >> 10]) : E;
  int j = lane * 2;
  float a0 = 0.0f, a1 = 0.0f, c0 = 0.0f, c1 = 0.0f;
  int i = start;
  for (; i + 2 <= end; i += 2) {
    int s0 = swv[i], s1 = swv[i + 1];
    float aa = awv[i], ab = awv[i + 1];
    int p0 = posb[i], p1 = posb[i + 1];
    float2 h0 = *(const float2*)(h + (size_t)s0 * HID + j);
    float2 A0 = *(const float2*)(tabA + (size_t)p0 * HID + j);
    float2 B0 = *(const float2*)(tabB + (size_t)p0 * HID + j);
    float2 h1 = *(const float2*)(h + (size_t)s1 * HID + j);
    float2 A1 = *(const float2*)(tabA + (size_t)p1 * HID + j);
    float2 B1 = *(const float2*)(tabB + (size_t)p1 * HID + j);
    a0 += fmaxf(h0.x + fmaf(A0.x, aa, B0.x), 0.0f);
    a1 += fmaxf(h0.y + fmaf(A0.y, aa, B0.y), 0.0f);
    c0 += fmaxf(h1.x + fmaf(A1.x, ab, B1.x), 0.0f);
    c1 += fmaxf(h1.y + fmaf(A1.y, ab, B1.y), 0.0f);
  }
  if (i < end) {
    int s0 = swv[i];
    float aa = awv[i];
    int p0 = posb[i];
    float2 h0 = *(const float2*)(h + (size_t)s0 * HID + j);
    float2 A0 = *(const float2*)(tabA + (size_t)p0 * HID + j);
    float2 B0 = *(const float2*)(tabB + (size_t)p0 * HID + j);
    a0 += fmaxf(h0.x + fmaf(A0.x, aa, B0.x), 0.0f);
    a1 += fmaxf(h0.y + fmaf(A0.y, aa, B0.y), 0.0f);
  }
  a0 += c0;
  a1 += c1;
  float ep1 = 1.0f + *epsP;
  float2 hn = *(const float2*)(h + (size_t)w * HID + j);
  float2 o;
  o.x = fmaf(ep1, hn.x, a0);
  o.y = fmaf(ep1, hn.y, a1);
  *(float2*)(zin + (size_t)w * HID + j) = o;
}

// ------------- weight pack into B-fragment layout (bf16) -------------
// frag f = mt*KS + ks; per lane: col = mt*16 + (lane&15), k = ks*32+(lane>>4)*8+i
__device__ __forceinline__ void pack_one(const float* __restrict__ W, int K, int M,
                                         int t, unsigned short* __restrict__ out) {
  int lane = t & 63, f = t >> 6;
  int KS = K >> 5;
  int mt = f / KS, ks = f - mt * KS;
  int col = mt * 16 + (lane & 15);
  int kb = ks * 32 + ((lane >> 4) * 8);
  unsigned r0 = 0, r1 = 0, r2 = 0, r3 = 0;
  r0 = bf16rne(W[(size_t)(kb + 0) * M + col]) | ((unsigned)bf16rne(W[(size_t)(kb + 1) * M + col]) << 16);
  r1 = bf16rne(W[(size_t)(kb + 2) * M + col]) | ((unsigned)bf16rne(W[(size_t)(kb + 3) * M + col]) << 16);
  r2 = bf16rne(W[(size_t)(kb + 4) * M + col]) | ((unsigned)bf16rne(W[(size_t)(kb + 5) * M + col]) << 16);
  r3 = bf16rne(W[(size_t)(kb + 6) * M + col]) | ((unsigned)bf16rne(W[(size_t)(kb + 7) * M + col]) << 16);
  uint4 v = make_uint4(r0, r1, r2, r3);
  *(uint4*)(out + ((size_t)f * 64 + lane) * 8) = v;
}

__global__ __launch_bounds__(256) void k_pack(
    const float* __restrict__ lin_W, const float* __restrict__ m1_W,
    const float* __restrict__ m2_W, unsigned short* __restrict__ pk_lin,
    unsigned short* __restrict__ pk_m1, unsigned short* __restrict__ pk_m2) {
  int t = blockIdx.x * 256 + threadIdx.x;
  if (t < 2048) {
    pack_one(lin_W, 128, 128, t, pk_lin);
  } else if (t < 10240) {
    int u = t - 2048;
    int l = u >> 12;
    pack_one(m1_W + (size_t)l * 128 * 256, 128, 256, u & 4095, pk_m1 + (size_t)l * 32768);
  } else if (t < 18432) {
    int u = t - 10240;
    int l = u >> 12;
    pack_one(m2_W + (size_t)l * 256 * 128, 256, 128, u & 4095, pk_m2 + (size_t)l * 32768);
  }
}

// ---------------- MFMA skinny GEMM: out = pre(in) @ W + bias ----------------
// Wave = 16 rows x full M. A frags built in regs from fp32; B from packed bf16.
// MODE 0: epilogue agg_edge(last_dst/last_src, enc)
// MODE 1: store z2 + BN partial sums (LDS block-reduce -> pS1/pS2, NO atomics)
// MODE 2: pre-op relu(in*scale+shift); optional relu on store
template <int K, int M, int MODE, bool RELU_OUT>
__global__ __launch_bounds__(256) void k_mgemm(
    const float* __restrict__ in0, const unsigned short* __restrict__ pkW,
    const float* __restrict__ bias, float* __restrict__ out,
    const float* __restrict__ pre_a, const float* __restrict__ pre_b,
    float* __restrict__ pS1, float* __restrict__ pS2,
    const int* __restrict__ last_dst, const int* __restrict__ last_src,
    const float* __restrict__ ea, const float* __restrict__ encW,
    const float* __restrict__ encb) {
  constexpr int KS = K / 32, MT = M / 16;
  __shared__ float red[(MODE == 1) ? 2048 : 1];  // [2][4 waves][256 cols]
  const int t = threadIdx.x;
  const int w = t >> 6, lane = t & 63;
  const int row0 = blockIdx.x * 64 + w * 16;
  const int arow = row0 + (lane & 15);
  const int rg = arow < N_NODES ? arow : N_NODES - 1;
  const int kb = (lane >> 4) * 8;

  short8v afrag[KS];
#pragma unroll
  for (int ks = 0; ks < KS; ++ks) {
    const int k0 = ks * 32 + kb;
    float4 v0 = *(const float4*)(in0 + (size_t)rg * K + k0);
    float4 v1 = *(const float4*)(in0 + (size_t)rg * K + k0 + 4);
    if (MODE == 2) {
      float4 sa0 = *(const float4*)(pre_a + k0);
      float4 sa1 = *(const float4*)(pre_a + k0 + 4);
      float4 sb0 = *(const float4*)(pre_b + k0);
      float4 sb1 = *(const float4*)(pre_b + k0 + 4);
      v0.x = fmaxf(fmaf(v0.x, sa0.x, sb0.x), 0.0f);
      v0.y = fmaxf(fmaf(v0.y, sa0.y, sb0.y), 0.0f);
      v0.z = fmaxf(fmaf(v0.z, sa0.z, sb0.z), 0.0f);
      v0.w = fmaxf(fmaf(v0.w, sa0.w, sb0.w), 0.0f);
      v1.x = fmaxf(fmaf(v1.x, sa1.x, sb1.x), 0.0f);
      v1.y = fmaxf(fmaf(v1.y, sa1.y, sb1.y), 0.0f);
      v1.z = fmaxf(fmaf(v1.z, sa1.z, sb1.z), 0.0f);
      v1.w = fmaxf(fmaf(v1.w, sa1.w, sb1.w), 0.0f);
    }
    short8v a;
    a[0] = (short)bf16rne(v0.x); a[1] = (short)bf16rne(v0.y);
    a[2] = (short)bf16rne(v0.z); a[3] = (short)bf16rne(v0.w);
    a[4] = (short)bf16rne(v1.x); a[5] = (short)bf16rne(v1.y);
    a[6] = (short)bf16rne(v1.z); a[7] = (short)bf16rne(v1.w);
    afrag[ks] = a;
  }

  f32x4 acc[MT];
#pragma unroll
  for (int mt = 0; mt < MT; ++mt) acc[mt] = (f32x4){0.f, 0.f, 0.f, 0.f};
#pragma unroll
  for (int mt = 0; mt < MT; ++mt) {
#pragma unroll
    for (int ks = 0; ks < KS; ++ks) {
      short8v bfrag = *(const short8v*)(pkW + ((size_t)(mt * KS + ks) * 64 + lane) * 8);
      acc[mt] = __builtin_amdgcn_mfma_f32_16x16x32_bf16(afrag[ks], bfrag, acc[mt], 0, 0, 0);
    }
  }

  // epilogue: C/D layout col = lane&15, row = (lane>>4)*4 + reg
  const int colb = lane & 15;
  const int rbase = row0 + (lane >> 4) * 4;
#pragma unroll
  for (int mt = 0; mt < MT; ++mt) {
    const int col = mt * 16 + colb;
    const float b = bias[col];
    if (MODE == 1) {
      float s1 = 0.0f, s2 = 0.0f;
#pragma unroll
      for (int r = 0; r < 4; ++r) {
        int R = rbase + r;
        if (R < N_NODES) {
          float v = acc[mt][r] + b;
          out[(size_t)R * M + col] = v;
          s1 += v;
          s2 = fmaf(v, v, s2);
        }
      }
      s1 += __shfl_xor(s1, 16);
      s1 += __shfl_xor(s1, 32);
      s2 += __shfl_xor(s2, 16);
      s2 += __shfl_xor(s2, 32);
      if (lane < 16) {
        red[w * 256 + col] = s1;
        red[1024 + w * 256 + col] = s2;
      }
    } else if (MODE == 2) {
#pragma unroll
      for (int r = 0; r < 4; ++r) {
        int R = rbase + r;
        if (R < N_NODES) {
          float v = acc[mt][r] + b;
          if (RELU_OUT) v = fmaxf(v, 0.0f);
          out[(size_t)R * M + col] = v;
        }
      }
    } else {
      const float ew = encW[col], eb = encb[col];
#pragma unroll
      for (int r = 0; r < 4; ++r) {
        int R = rbase + r;
        if (R < N_NODES) {
          float v = acc[mt][r] + b;
          int ld = last_dst[R];
          int ls = last_src[R];
          int e = (ld >= 0) ? ld : ls;  // dst assignment overwrites src assignment
          if (e >= 0) v = fmaxf(v + fmaf(ea[e], ew, eb), 0.0f);
          out[(size_t)R * M + col] = v;
        }
      }
    }
  }
  if (MODE == 1) {
    __syncthreads();
    if (t < 256) {
      float a = red[t] + red[256 + t] + red[512 + t] + red[768 + t];
      float q = red[1024 + t] + red[1280 + t] + red[1536 + t] + red[1792 + t];
      pS1[(size_t)blockIdx.x * 256 + t] = a;
      pS2[(size_t)blockIdx.x * 256 + t] = q;
    }
  }
}

// ------- BN finalize: reduce per-block partials, emit scale/shift per column -------
__global__ __launch_bounds__(1024) void k_bnfin(
    const float* __restrict__ pS1, const float* __restrict__ pS2,
    const float* __restrict__ g, const float* __restrict__ bb,
    float* __restrict__ scale, float* __restrict__ shift, int nblk) {
  __shared__ float r1[1024], r2[1024];
  int t = threadIdx.x;        // 1024 threads
  int gq = t >> 8, j = t & 255;
  float s1 = 0.0f, s2 = 0.0f;
  for (int b = gq; b < nblk; b += 4) {
    s1 += pS1[(size_t)b * 256 + j];
    s2 += pS2[(size_t)b * 256 + j];
  }
  r1[t] = s1;
  r2[t] = s2;
  __syncthreads();
  if (t < 256) {
    float a = r1[t] + r1[256 + t] + r1[512 + t] + r1[768 + t];
    float q = r2[t] + r2[256 + t] + r2[512 + t] + r2[768 + t];
    const float inv = 1.0f / (float)N_NODES;
    float mu = a * inv;
    float var = q * inv - mu * mu;
    float sc = g[t] * rsqrtf(var + 1e-5f);
    scale[t] = sc;
    shift[t] = fmaf(-mu, sc, bb[t]);
  }
}

extern "C" void kernel_launch(void* const* d_in, const int* in_sizes, int n_in,
                              void* d_out, int out_size, void* d_ws, size_t ws_size,
                              hipStream_t stream) {
  const float* x     = (const float*)d_in[0];
  const int*   ei    = (const int*)d_in[1];
  const float* ea    = (const float*)d_in[2];
  const float* lin_W = (const float*)d_in[3];
  const float* lin_b = (const float*)d_in[4];
  const float* enc_W = (const float*)d_in[5];
  const float* enc_b = (const float*)d_in[6];
  const float* eps   = (const float*)d_in[7];
  const float* e1_W  = (const float*)d_in[8];
  const float* e1_b  = (const float*)d_in[9];
  const float* e2_W  = (const float*)d_in[10];
  const float* e2_b  = (const float*)d_in[11];
  const float* m1_W  = (const float*)d_in[12];
  const float* m1_b  = (const float*)d_in[13];
  const float* bn_g  = (const float*)d_in[14];
  const float* bn_b  = (const float*)d_in[15];
  const float* m2_W  = (const float*)d_in[16];
  const float* m2_b  = (const float*)d_in[17];
  float* hbuf = (float*)d_out;  // h lives in d_out; final GEMM2 overwrites it

  const int NB_SCAN = (N_NODES + 1023) / 1024;  // 98
  const int NB_GEMM = (N_NODES + 63) / 64;      // 1563

  float* ws = (float*)d_ws;
  size_t o = 0;
  float* zin = ws;                 o += (size_t)N_NODES * 128;
  float* z2 = ws + o;              o += (size_t)N_NODES * 256;
  int* last_dst = (int*)(ws + o);  o += N_NODES;
  int* last_src = (int*)(ws + o);  o += N_NODES;
  int* deg = (int*)(ws + o);       o += N_NODES;
  int* cnt = (int*)(ws + o);       o += N_NODES;
  int* excl = (int*)(ws + o);      o += N_NODES;
  int* bsum = (int*)(ws + o);      o += 128;
  int* boff = (int*)(ws + o);      o += 128;
  int* swv = (int*)(ws + o);       o += E_EDGES;
  float* awv = ws + o;             o += E_EDGES;
  unsigned char* posb = (unsigned char*)(ws + o); o += (E_EDGES + 3) / 4 + 4;
  float* tabA = ws + o;            o += 129 * 128;
  float* tabB = ws + o;            o += 129 * 128;
  float* tsort = ws + o;           o += 128;
  float* pS1 = ws + o;             o += (size_t)NB_GEMM * 256;
  float* pS2 = ws + o;             o += (size_t)NB_GEMM * 256;
  float* scale = ws + o;           o += 256;
  float* shift = ws + o;           o += 256;
  unsigned short* pk_lin = (unsigned short*)(ws + o); o += 8192;   // 16384 bf16
  unsigned short* pk_m1  = (unsigned short*)(ws + o); o += 32768;  // 2 x 32768 bf16
  unsigned short* pk_m2  = (unsigned short*)(ws + o); o += 32768;  // 2 x 32768 bf16
  if (ws_size < o * sizeof(float)) return;

  hipMemsetAsync(last_dst, 0xFF, 2 * (size_t)N_NODES * sizeof(int), stream);
  hipMemsetAsync(deg, 0, 2 * (size_t)N_NODES * sizeof(int), stream);  // deg + cnt
  k_last<<<(E_EDGES + 255) / 256, 256, 0, stream>>>(ei, last_src, last_dst, deg, E_EDGES);
  k_scan1<<<NB_SCAN, 256, 0, stream>>>(deg, excl, bsum, N_NODES);
  k_scan2<<<1, 128, 0, stream>>>(bsum, boff, NB_SCAN);
  k_scatter<<<(E_EDGES + 255) / 256, 256, 0, stream>>>(ei, ea, excl, boff, cnt, swv, awv, E_EDGES);
  k_pack<<<72, 256, 0, stream>>>(lin_W, m1_W, m2_W, pk_lin, pk_m1, pk_m2);

  // h = x @ lin_W + lin_b, then agg_edge epilogue
  k_mgemm<128, 128, 0, false><<<NB_GEMM, 256, 0, stream>>>(
      x, pk_lin, lin_b, hbuf, nullptr, nullptr, nullptr, nullptr,
      last_dst, last_src, ea, enc_W, enc_b);

  for (int l = 0; l < 2; ++l) {
    k_table<<<1, 128, 0, stream>>>(e1_W + l * 128, e1_b + l * 128,
                                   e2_W + l * 128 * 128, e2_b + l * 128,
                                   tabA, tabB, tsort);
    k_pos<<<(E_EDGES + 255) / 256, 256, 0, stream>>>(awv, tsort, posb, E_EDGES);
    k_agg<<<(N_NODES * 64 + 255) / 256, 256, 0, stream>>>(
        hbuf, swv, awv, posb, excl, boff, tabA, tabB, eps + l, zin, N_NODES, E_EDGES);
    k_mgemm<128, 256, 1, false><<<NB_GEMM, 256, 0, stream>>>(
        zin, pk_m1 + (size_t)l * 32768, m1_b + l * 256, z2, nullptr, nullptr,
        pS1, pS2, nullptr, nullptr, nullptr, nullptr, nullptr);
    k_bnfin<<<1, 1024, 0, stream>>>(pS1, pS2, bn_g + l * 256, bn_b + l * 256,
                                    scale, shift, NB_GEMM);
    if (l == 0) {
      k_mgemm<256, 128, 2, true><<<NB_GEMM, 256, 0, stream>>>(
          z2, pk_m2 + (size_t)l * 32768, m2_b + l * 128, hbuf, scale, shift,
          nullptr, nullptr, nullptr, nullptr, nullptr, nullptr, nullptr);
    } else {
      k_mgemm<256, 128, 2, false><<<NB_GEMM, 256, 0, stream>>>(
          z2, pk_m2 + (size_t)l * 32768, m2_b + l * 128, hbuf, scale, shift,
          nullptr, nullptr, nullptr, nullptr, nullptr, nullptr, nullptr);
    }
  }
}

// Round 7
// 807.222 us; speedup vs baseline: 2.1139x; 1.2490x over previous
//
#include <hip/hip_runtime.h>

#define N_NODES 100000
#define E_EDGES 600000
#define HID 128

typedef __attribute__((ext_vector_type(8))) short short8v;
typedef __attribute__((ext_vector_type(4))) float f32x4;

__device__ __forceinline__ unsigned short bf16rne(float x) {
  unsigned u = __float_as_uint(x);
  return (unsigned short)((u + 0x7FFFu + ((u >> 16) & 1u)) >> 16);
}

// ------------- last-edge (last-write-wins) + dst-degree histogram -------------
__global__ void k_last(const int* __restrict__ ei, int* __restrict__ last_src,
                       int* __restrict__ last_dst, int* __restrict__ deg, int E) {
  int e = blockIdx.x * blockDim.x + threadIdx.x;
  if (e >= E) return;
  int s = ei[e], d = ei[E + e];
  atomicMax(&last_src[s], e);
  atomicMax(&last_dst[d], e);
  atomicAdd(&deg[d], 1);
}

// ------------- 2-level exclusive scan over deg (CSR row offsets) -------------
__global__ __launch_bounds__(256) void k_scan1(const int* __restrict__ deg,
                                               int* __restrict__ excl,
                                               int* __restrict__ bsum, int n) {
  __shared__ int sh[256];
  int b = blockIdx.x, t = threadIdx.x;
  int i0 = b * 1024 + t * 4;
  int v0 = (i0 + 0 < n) ? deg[i0 + 0] : 0;
  int v1 = (i0 + 1 < n) ? deg[i0 + 1] : 0;
  int v2 = (i0 + 2 < n) ? deg[i0 + 2] : 0;
  int v3 = (i0 + 3 < n) ? deg[i0 + 3] : 0;
  int tsum = v0 + v1 + v2 + v3;
  sh[t] = tsum;
  __syncthreads();
  for (int off = 1; off < 256; off <<= 1) {
    int add = (t >= off) ? sh[t - off] : 0;
    __syncthreads();
    sh[t] += add;
    __syncthreads();
  }
  int ex = sh[t] - tsum;
  if (i0 + 0 < n) excl[i0 + 0] = ex;
  if (i0 + 1 < n) excl[i0 + 1] = ex + v0;
  if (i0 + 2 < n) excl[i0 + 2] = ex + v0 + v1;
  if (i0 + 3 < n) excl[i0 + 3] = ex + v0 + v1 + v2;
  if (t == 255) bsum[b] = sh[255];
}

__global__ void k_scan2(const int* __restrict__ bsum, int* __restrict__ boff, int nb) {
  __shared__ int sh[128];
  int t = threadIdx.x;
  int v = (t < nb) ? bsum[t] : 0;
  sh[t] = v;
  __syncthreads();
  for (int off = 1; off < 128; off <<= 1) {
    int add = (t >= off) ? sh[t - off] : 0;
    __syncthreads();
    sh[t] += add;
    __syncthreads();
  }
  if (t < nb) boff[t] = sh[t] - v;
}

// ------------- scatter edges into dst buckets: (src, attr) pairs -------------
__global__ void k_scatter(const int* __restrict__ ei, const float* __restrict__ ea,
                          const int* __restrict__ excl, const int* __restrict__ boff,
                          int* __restrict__ cnt, int* __restrict__ swv,
                          float* __restrict__ awv, int E) {
  int e = blockIdx.x * blockDim.x + threadIdx.x;
  if (e >= E) return;
  int d = ei[E + e];
  int p = excl[d] + boff[d >> 10] + atomicAdd(&cnt[d], 1);
  swv[p] = ei[e];
  awv[p] = ea[e];
}

// ---------------- piecewise-linear edge-encoder table ----------------
__global__ void k_table(const float* __restrict__ W1g, const float* __restrict__ b1g,
                        const float* __restrict__ W2g, const float* __restrict__ b2g,
                        float* __restrict__ tabA, float* __restrict__ tabB,
                        float* __restrict__ tsort) {
  __shared__ float w1[128], b1[128], key[128];
  __shared__ int idx[128];
  __shared__ float w2[128][128];
  const int t = threadIdx.x;  // 128 threads
  w1[t] = W1g[t];
  b1[t] = b1g[t];
  for (int k = 0; k < 128; ++k) w2[k][t] = W2g[k * 128 + t];
  __syncthreads();
  float s0 = w1[t];
  key[t] = (s0 != 0.0f) ? (-b1[t] / s0) : __builtin_inff();
  idx[t] = t;
  for (int size = 2; size <= 128; size <<= 1) {
    for (int stride = size >> 1; stride > 0; stride >>= 1) {
      __syncthreads();
      int p = t ^ stride;
      if (p > t) {
        bool up = ((t & size) == 0);
        float k1 = key[t], k2 = key[p];
        if (up == (k1 > k2)) {
          int i1 = idx[t], i2 = idx[p];
          key[t] = k2; key[p] = k1; idx[t] = i2; idx[p] = i1;
        }
      }
    }
  }
  __syncthreads();
  tsort[t] = key[t];
  float A = 0.0f, B = b2g[t];
  for (int k = 0; k < 128; ++k) {
    float s = w1[k], bb = b1[k], w = w2[k][t];
    if (s < 0.0f) { A = fmaf(s, w, A); B = fmaf(bb, w, B); }
    else if (s == 0.0f && bb > 0.0f) { B = fmaf(bb, w, B); }
  }
  tabA[t] = A;
  tabB[t] = B;
  for (int i = 0; i < 128; ++i) {
    float kv = key[i];
    int kk = idx[i];
    if (kv < __builtin_inff()) {
      float s = w1[kk], bb = b1[kk], w = w2[kk][t];
      if (s > 0.0f) { A = fmaf(s, w, A); B = fmaf(bb, w, B); }
      else { A = fmaf(-s, w, A); B = fmaf(-bb, w, B); }
    }
    tabA[(i + 1) * 128 + t] = A;
    tabB[(i + 1) * 128 + t] = B;
  }
}

// ------------- per-edge interval index (removes search from k_agg) -------------
__global__ __launch_bounds__(256) void k_pos(const float* __restrict__ awv,
                                             const float* __restrict__ tsort,
                                             unsigned char* __restrict__ posb, int E) {
  __shared__ float ts[128];
  if (threadIdx.x < 128) ts[threadIdx.x] = tsort[threadIdx.x];
  __syncthreads();
  int i = blockIdx.x * blockDim.x + threadIdx.x;
  if (i >= E) return;
  float a = awv[i];
  int pos = 0;
#pragma unroll
  for (int st = 64; st > 0; st >>= 1)
    if (pos + st <= 128 && ts[pos + st - 1] < a) pos += st;
  posb[i] = (unsigned char)pos;
}

// ------- per-node gather-aggregate: zin[n] = (1+eps)*h[n] + sum relu(...) -------
__global__ __launch_bounds__(256) void k_agg(
    const float* __restrict__ h, const int* __restrict__ swv,
    const float* __restrict__ awv, const unsigned char* __restrict__ posb,
    const int* __restrict__ excl, const int* __restrict__ boff,
    const float* __restrict__ tabA, const float* __restrict__ tabB,
    const float* __restrict__ epsP, float* __restrict__ zin, int N, int E) {
  int w = (int)((blockIdx.x * 256 + threadIdx.x) >> 6);  // one wave per node
  if (w >= N) return;
  int lane = threadIdx.x & 63;
  int start = excl[w] + boff[w >> 10];
  int end = (w + 1 < N) ? (excl[w + 1] + boff[(w + 1) >> 10]) : E;
  int j = lane * 2;
  float a0 = 0.0f, a1 = 0.0f, c0 = 0.0f, c1 = 0.0f;
  int i = start;
  for (; i + 2 <= end; i += 2) {
    int s0 = swv[i], s1 = swv[i + 1];
    float aa = awv[i], ab = awv[i + 1];
    int p0 = posb[i], p1 = posb[i + 1];
    float2 h0 = *(const float2*)(h + (size_t)s0 * HID + j);
    float2 A0 = *(const float2*)(tabA + (size_t)p0 * HID + j);
    float2 B0 = *(const float2*)(tabB + (size_t)p0 * HID + j);
    float2 h1 = *(const float2*)(h + (size_t)s1 * HID + j);
    float2 A1 = *(const float2*)(tabA + (size_t)p1 * HID + j);
    float2 B1 = *(const float2*)(tabB + (size_t)p1 * HID + j);
    a0 += fmaxf(h0.x + fmaf(A0.x, aa, B0.x), 0.0f);
    a1 += fmaxf(h0.y + fmaf(A0.y, aa, B0.y), 0.0f);
    c0 += fmaxf(h1.x + fmaf(A1.x, ab, B1.x), 0.0f);
    c1 += fmaxf(h1.y + fmaf(A1.y, ab, B1.y), 0.0f);
  }
  if (i < end) {
    int s0 = swv[i];
    float aa = awv[i];
    int p0 = posb[i];
    float2 h0 = *(const float2*)(h + (size_t)s0 * HID + j);
    float2 A0 = *(const float2*)(tabA + (size_t)p0 * HID + j);
    float2 B0 = *(const float2*)(tabB + (size_t)p0 * HID + j);
    a0 += fmaxf(h0.x + fmaf(A0.x, aa, B0.x), 0.0f);
    a1 += fmaxf(h0.y + fmaf(A0.y, aa, B0.y), 0.0f);
  }
  a0 += c0;
  a1 += c1;
  float ep1 = 1.0f + *epsP;
  float2 hn = *(const float2*)(h + (size_t)w * HID + j);
  float2 o;
  o.x = fmaf(ep1, hn.x, a0);
  o.y = fmaf(ep1, hn.y, a1);
  *(float2*)(zin + (size_t)w * HID + j) = o;
}

// ------------- weight pack into B-fragment layout (bf16) -------------
// frag f = mt*KS + ks; per lane: col = mt*16 + (lane&15), k = ks*32+(lane>>4)*8+i
__device__ __forceinline__ void pack_one(const float* __restrict__ W, int K, int M,
                                         int t, unsigned short* __restrict__ out) {
  int lane = t & 63, f = t >> 6;
  int KS = K >> 5;
  int mt = f / KS, ks = f - mt * KS;
  int col = mt * 16 + (lane & 15);
  int kb = ks * 32 + ((lane >> 4) * 8);
  unsigned r0 = 0, r1 = 0, r2 = 0, r3 = 0;
  r0 = bf16rne(W[(size_t)(kb + 0) * M + col]) | ((unsigned)bf16rne(W[(size_t)(kb + 1) * M + col]) << 16);
  r1 = bf16rne(W[(size_t)(kb + 2) * M + col]) | ((unsigned)bf16rne(W[(size_t)(kb + 3) * M + col]) << 16);
  r2 = bf16rne(W[(size_t)(kb + 4) * M + col]) | ((unsigned)bf16rne(W[(size_t)(kb + 5) * M + col]) << 16);
  r3 = bf16rne(W[(size_t)(kb + 6) * M + col]) | ((unsigned)bf16rne(W[(size_t)(kb + 7) * M + col]) << 16);
  uint4 v = make_uint4(r0, r1, r2, r3);
  *(uint4*)(out + ((size_t)f * 64 + lane) * 8) = v;
}

__global__ __launch_bounds__(256) void k_pack(
    const float* __restrict__ lin_W, const float* __restrict__ m1_W,
    const float* __restrict__ m2_W, unsigned short* __restrict__ pk_lin,
    unsigned short* __restrict__ pk_m1, unsigned short* __restrict__ pk_m2) {
  int t = blockIdx.x * 256 + threadIdx.x;
  if (t < 2048) {
    pack_one(lin_W, 128, 128, t, pk_lin);
  } else if (t < 10240) {
    int u = t - 2048;
    int l = u >> 12;
    pack_one(m1_W + (size_t)l * 128 * 256, 128, 256, u & 4095, pk_m1 + (size_t)l * 32768);
  } else if (t < 18432) {
    int u = t - 10240;
    int l = u >> 12;
    pack_one(m2_W + (size_t)l * 256 * 128, 256, 128, u & 4095, pk_m2 + (size_t)l * 32768);
  }
}

// ---------------- MFMA skinny GEMM: out = pre(in) @ W + bias ----------------
// Wave = 16 rows x full M. A frags built in regs from fp32; B from packed bf16.
// MODE 0: epilogue agg_edge(last_dst/last_src, enc)
// MODE 1: store z2 + BN partial sums (LDS block-reduce -> pS1/pS2, NO atomics)
// MODE 2: pre-op relu(in*scale+shift); optional relu on store
template <int K, int M, int MODE, bool RELU_OUT>
__global__ __launch_bounds__(256) void k_mgemm(
    const float* __restrict__ in0, const unsigned short* __restrict__ pkW,
    const float* __restrict__ bias, float* __restrict__ out,
    const float* __restrict__ pre_a, const float* __restrict__ pre_b,
    float* __restrict__ pS1, float* __restrict__ pS2,
    const int* __restrict__ last_dst, const int* __restrict__ last_src,
    const float* __restrict__ ea, const float* __restrict__ encW,
    const float* __restrict__ encb) {
  constexpr int KS = K / 32, MT = M / 16;
  __shared__ float red[(MODE == 1) ? 2048 : 1];  // [2][4 waves][256 cols]
  const int t = threadIdx.x;
  const int w = t >> 6, lane = t & 63;
  const int row0 = blockIdx.x * 64 + w * 16;
  const int arow = row0 + (lane & 15);
  const int rg = arow < N_NODES ? arow : N_NODES - 1;
  const int kb = (lane >> 4) * 8;

  short8v afrag[KS];
#pragma unroll
  for (int ks = 0; ks < KS; ++ks) {
    const int k0 = ks * 32 + kb;
    float4 v0 = *(const float4*)(in0 + (size_t)rg * K + k0);
    float4 v1 = *(const float4*)(in0 + (size_t)rg * K + k0 + 4);
    if (MODE == 2) {
      float4 sa0 = *(const float4*)(pre_a + k0);
      float4 sa1 = *(const float4*)(pre_a + k0 + 4);
      float4 sb0 = *(const float4*)(pre_b + k0);
      float4 sb1 = *(const float4*)(pre_b + k0 + 4);
      v0.x = fmaxf(fmaf(v0.x, sa0.x, sb0.x), 0.0f);
      v0.y = fmaxf(fmaf(v0.y, sa0.y, sb0.y), 0.0f);
      v0.z = fmaxf(fmaf(v0.z, sa0.z, sb0.z), 0.0f);
      v0.w = fmaxf(fmaf(v0.w, sa0.w, sb0.w), 0.0f);
      v1.x = fmaxf(fmaf(v1.x, sa1.x, sb1.x), 0.0f);
      v1.y = fmaxf(fmaf(v1.y, sa1.y, sb1.y), 0.0f);
      v1.z = fmaxf(fmaf(v1.z, sa1.z, sb1.z), 0.0f);
      v1.w = fmaxf(fmaf(v1.w, sa1.w, sb1.w), 0.0f);
    }
    short8v a;
    a[0] = (short)bf16rne(v0.x); a[1] = (short)bf16rne(v0.y);
    a[2] = (short)bf16rne(v0.z); a[3] = (short)bf16rne(v0.w);
    a[4] = (short)bf16rne(v1.x); a[5] = (short)bf16rne(v1.y);
    a[6] = (short)bf16rne(v1.z); a[7] = (short)bf16rne(v1.w);
    afrag[ks] = a;
  }

  f32x4 acc[MT];
#pragma unroll
  for (int mt = 0; mt < MT; ++mt) acc[mt] = (f32x4){0.f, 0.f, 0.f, 0.f};
#pragma unroll
  for (int mt = 0; mt < MT; ++mt) {
#pragma unroll
    for (int ks = 0; ks < KS; ++ks) {
      short8v bfrag = *(const short8v*)(pkW + ((size_t)(mt * KS + ks) * 64 + lane) * 8);
      acc[mt] = __builtin_amdgcn_mfma_f32_16x16x32_bf16(afrag[ks], bfrag, acc[mt], 0, 0, 0);
    }
  }

  // epilogue: C/D layout col = lane&15, row = (lane>>4)*4 + reg
  const int colb = lane & 15;
  const int rbase = row0 + (lane >> 4) * 4;
#pragma unroll
  for (int mt = 0; mt < MT; ++mt) {
    const int col = mt * 16 + colb;
    const float b = bias[col];
    if (MODE == 1) {
      float s1 = 0.0f, s2 = 0.0f;
#pragma unroll
      for (int r = 0; r < 4; ++r) {
        int R = rbase + r;
        if (R < N_NODES) {
          float v = acc[mt][r] + b;
          out[(size_t)R * M + col] = v;
          s1 += v;
          s2 = fmaf(v, v, s2);
        }
      }
      s1 += __shfl_xor(s1, 16);
      s1 += __shfl_xor(s1, 32);
      s2 += __shfl_xor(s2, 16);
      s2 += __shfl_xor(s2, 32);
      if (lane < 16) {
        red[w * 256 + col] = s1;
        red[1024 + w * 256 + col] = s2;
      }
    } else if (MODE == 2) {
#pragma unroll
      for (int r = 0; r < 4; ++r) {
        int R = rbase + r;
        if (R < N_NODES) {
          float v = acc[mt][r] + b;
          if (RELU_OUT) v = fmaxf(v, 0.0f);
          out[(size_t)R * M + col] = v;
        }
      }
    } else {
      const float ew = encW[col], eb = encb[col];
#pragma unroll
      for (int r = 0; r < 4; ++r) {
        int R = rbase + r;
        if (R < N_NODES) {
          float v = acc[mt][r] + b;
          int ld = last_dst[R];
          int ls = last_src[R];
          int e = (ld >= 0) ? ld : ls;  // dst assignment overwrites src assignment
          if (e >= 0) v = fmaxf(v + fmaf(ea[e], ew, eb), 0.0f);
          out[(size_t)R * M + col] = v;
        }
      }
    }
  }
  if (MODE == 1) {
    __syncthreads();
    if (t < 256) {
      float a = red[t] + red[256 + t] + red[512 + t] + red[768 + t];
      float q = red[1024 + t] + red[1280 + t] + red[1536 + t] + red[1792 + t];
      pS1[(size_t)blockIdx.x * 256 + t] = a;
      pS2[(size_t)blockIdx.x * 256 + t] = q;
    }
  }
}

// ------- BN finalize stage 1: 64 blocks reduce 1563 partials -> 64 partials -------
__global__ __launch_bounds__(256) void k_bnred(
    const float* __restrict__ pS1, const float* __restrict__ pS2,
    float* __restrict__ qS1, float* __restrict__ qS2, int nblk) {
  int j = threadIdx.x;  // 256
  int b = blockIdx.x;   // 64
  float s1 = 0.0f, s2 = 0.0f;
  for (int i = b; i < nblk; i += 64) {
    s1 += pS1[(size_t)i * 256 + j];
    s2 += pS2[(size_t)i * 256 + j];
  }
  qS1[b * 256 + j] = s1;
  qS2[b * 256 + j] = s2;
}

// ------- BN finalize stage 2: fold 64 partials, emit scale/shift -------
__global__ __launch_bounds__(256) void k_bnfin2(
    const float* __restrict__ qS1, const float* __restrict__ qS2,
    const float* __restrict__ g, const float* __restrict__ bb,
    float* __restrict__ scale, float* __restrict__ shift) {
  int j = threadIdx.x;  // 256
  float s1 = 0.0f, s2 = 0.0f;
#pragma unroll 8
  for (int i = 0; i < 64; ++i) {
    s1 += qS1[i * 256 + j];
    s2 += qS2[i * 256 + j];
  }
  const float inv = 1.0f / (float)N_NODES;
  float mu = s1 * inv;
  float var = s2 * inv - mu * mu;
  float sc = g[j] * rsqrtf(var + 1e-5f);
  scale[j] = sc;
  shift[j] = fmaf(-mu, sc, bb[j]);
}

extern "C" void kernel_launch(void* const* d_in, const int* in_sizes, int n_in,
                              void* d_out, int out_size, void* d_ws, size_t ws_size,
                              hipStream_t stream) {
  const float* x     = (const float*)d_in[0];
  const int*   ei    = (const int*)d_in[1];
  const float* ea    = (const float*)d_in[2];
  const float* lin_W = (const float*)d_in[3];
  const float* lin_b = (const float*)d_in[4];
  const float* enc_W = (const float*)d_in[5];
  const float* enc_b = (const float*)d_in[6];
  const float* eps   = (const float*)d_in[7];
  const float* e1_W  = (const float*)d_in[8];
  const float* e1_b  = (const float*)d_in[9];
  const float* e2_W  = (const float*)d_in[10];
  const float* e2_b  = (const float*)d_in[11];
  const float* m1_W  = (const float*)d_in[12];
  const float* m1_b  = (const float*)d_in[13];
  const float* bn_g  = (const float*)d_in[14];
  const float* bn_b  = (const float*)d_in[15];
  const float* m2_W  = (const float*)d_in[16];
  const float* m2_b  = (const float*)d_in[17];
  float* hbuf = (float*)d_out;  // h lives in d_out; final GEMM2 overwrites it

  const int NB_SCAN = (N_NODES + 1023) / 1024;  // 98
  const int NB_GEMM = (N_NODES + 63) / 64;      // 1563

  float* ws = (float*)d_ws;
  size_t o = 0;
  float* zin = ws;                 o += (size_t)N_NODES * 128;
  float* z2 = ws + o;              o += (size_t)N_NODES * 256;
  int* last_dst = (int*)(ws + o);  o += N_NODES;
  int* last_src = (int*)(ws + o);  o += N_NODES;
  int* deg = (int*)(ws + o);       o += N_NODES;
  int* cnt = (int*)(ws + o);       o += N_NODES;
  int* excl = (int*)(ws + o);      o += N_NODES;
  int* bsum = (int*)(ws + o);      o += 128;
  int* boff = (int*)(ws + o);      o += 128;
  int* swv = (int*)(ws + o);       o += E_EDGES;
  float* awv = ws + o;             o += E_EDGES;
  unsigned char* posb = (unsigned char*)(ws + o); o += (E_EDGES + 3) / 4 + 4;
  float* tabA = ws + o;            o += 129 * 128;
  float* tabB = ws + o;            o += 129 * 128;
  float* tsort = ws + o;           o += 128;
  float* pS1 = ws + o;             o += (size_t)NB_GEMM * 256;
  float* pS2 = ws + o;             o += (size_t)NB_GEMM * 256;
  float* qS1 = ws + o;             o += 64 * 256;
  float* qS2 = ws + o;             o += 64 * 256;
  float* scale = ws + o;           o += 256;
  float* shift = ws + o;           o += 256;
  unsigned short* pk_lin = (unsigned short*)(ws + o); o += 8192;   // 16384 bf16
  unsigned short* pk_m1  = (unsigned short*)(ws + o); o += 32768;  // 2 x 32768 bf16
  unsigned short* pk_m2  = (unsigned short*)(ws + o); o += 32768;  // 2 x 32768 bf16
  if (ws_size < o * sizeof(float)) return;

  hipMemsetAsync(last_dst, 0xFF, 2 * (size_t)N_NODES * sizeof(int), stream);
  hipMemsetAsync(deg, 0, 2 * (size_t)N_NODES * sizeof(int), stream);  // deg + cnt
  k_last<<<(E_EDGES + 255) / 256, 256, 0, stream>>>(ei, last_src, last_dst, deg, E_EDGES);
  k_scan1<<<NB_SCAN, 256, 0, stream>>>(deg, excl, bsum, N_NODES);
  k_scan2<<<1, 128, 0, stream>>>(bsum, boff, NB_SCAN);
  k_scatter<<<(E_EDGES + 255) / 256, 256, 0, stream>>>(ei, ea, excl, boff, cnt, swv, awv, E_EDGES);
  k_pack<<<72, 256, 0, stream>>>(lin_W, m1_W, m2_W, pk_lin, pk_m1, pk_m2);

  // h = x @ lin_W + lin_b, then agg_edge epilogue
  k_mgemm<128, 128, 0, false><<<NB_GEMM, 256, 0, stream>>>(
      x, pk_lin, lin_b, hbuf, nullptr, nullptr, nullptr, nullptr,
      last_dst, last_src, ea, enc_W, enc_b);

  for (int l = 0; l < 2; ++l) {
    k_table<<<1, 128, 0, stream>>>(e1_W + l * 128, e1_b + l * 128,
                                   e2_W + l * 128 * 128, e2_b + l * 128,
                                   tabA, tabB, tsort);
    k_pos<<<(E_EDGES + 255) / 256, 256, 0, stream>>>(awv, tsort, posb, E_EDGES);
    k_agg<<<(N_NODES * 64 + 255) / 256, 256, 0, stream>>>(
        hbuf, swv, awv, posb, excl, boff, tabA, tabB, eps + l, zin, N_NODES, E_EDGES);
    k_mgemm<128, 256, 1, false><<<NB_GEMM, 256, 0, stream>>>(
        zin, pk_m1 + (size_t)l * 32768, m1_b + l * 256, z2, nullptr, nullptr,
        pS1, pS2, nullptr, nullptr, nullptr, nullptr, nullptr);
    k_bnred<<<64, 256, 0, stream>>>(pS1, pS2, qS1, qS2, NB_GEMM);
    k_bnfin2<<<1, 256, 0, stream>>>(qS1, qS2, bn_g + l * 256, bn_b + l * 256,
                                    scale, shift);
    if (l == 0) {
      k_mgemm<256, 128, 2, true><<<NB_GEMM, 256, 0, stream>>>(
          z2, pk_m2 + (size_t)l * 32768, m2_b + l * 128, hbuf, scale, shift,
          nullptr, nullptr, nullptr, nullptr, nullptr, nullptr, nullptr);
    } else {
      k_mgemm<256, 128, 2, false><<<NB_GEMM, 256, 0, stream>>>(
          z2, pk_m2 + (size_t)l * 32768, m2_b + l * 128, hbuf, scale, shift,
          nullptr, nullptr, nullptr, nullptr, nullptr, nullptr, nullptr);
    }
  }
}

// Round 8
// 686.872 us; speedup vs baseline: 2.4843x; 1.1752x over previous
//
#include <hip/hip_runtime.h>

#define N_NODES 100000
#define E_EDGES 600000
#define HID 128

typedef __attribute__((ext_vector_type(8))) short short8v;
typedef __attribute__((ext_vector_type(4))) float f32x4;

__device__ __forceinline__ unsigned short bf16rne(float x) {
  unsigned u = __float_as_uint(x);
  return (unsigned short)((u + 0x7FFFu + ((u >> 16) & 1u)) >> 16);
}
__device__ __forceinline__ float bf16tof(unsigned short u) {
  return __uint_as_float(((unsigned)u) << 16);
}

// ------------- last-edge (last-write-wins) + dst-degree histogram -------------
__global__ void k_last(const int* __restrict__ ei, int* __restrict__ last_src,
                       int* __restrict__ last_dst, int* __restrict__ deg, int E) {
  int e = blockIdx.x * blockDim.x + threadIdx.x;
  if (e >= E) return;
  int s = ei[e], d = ei[E + e];
  atomicMax(&last_src[s], e);
  atomicMax(&last_dst[d], e);
  atomicAdd(&deg[d], 1);
}

// ------------- 2-level exclusive scan over deg (CSR row offsets) -------------
__global__ __launch_bounds__(256) void k_scan1(const int* __restrict__ deg,
                                               int* __restrict__ excl,
                                               int* __restrict__ bsum, int n) {
  __shared__ int sh[256];
  int b = blockIdx.x, t = threadIdx.x;
  int i0 = b * 1024 + t * 4;
  int v0 = (i0 + 0 < n) ? deg[i0 + 0] : 0;
  int v1 = (i0 + 1 < n) ? deg[i0 + 1] : 0;
  int v2 = (i0 + 2 < n) ? deg[i0 + 2] : 0;
  int v3 = (i0 + 3 < n) ? deg[i0 + 3] : 0;
  int tsum = v0 + v1 + v2 + v3;
  sh[t] = tsum;
  __syncthreads();
  for (int off = 1; off < 256; off <<= 1) {
    int add = (t >= off) ? sh[t - off] : 0;
    __syncthreads();
    sh[t] += add;
    __syncthreads();
  }
  int ex = sh[t] - tsum;
  if (i0 + 0 < n) excl[i0 + 0] = ex;
  if (i0 + 1 < n) excl[i0 + 1] = ex + v0;
  if (i0 + 2 < n) excl[i0 + 2] = ex + v0 + v1;
  if (i0 + 3 < n) excl[i0 + 3] = ex + v0 + v1 + v2;
  if (t == 255) bsum[b] = sh[255];
}

__global__ void k_scan2(const int* __restrict__ bsum, int* __restrict__ boff, int nb) {
  __shared__ int sh[128];
  int t = threadIdx.x;
  int v = (t < nb) ? bsum[t] : 0;
  sh[t] = v;
  __syncthreads();
  for (int off = 1; off < 128; off <<= 1) {
    int add = (t >= off) ? sh[t - off] : 0;
    __syncthreads();
    sh[t] += add;
    __syncthreads();
  }
  if (t < nb) boff[t] = sh[t] - v;
}

// ------------- scatter edges into dst buckets: (src, attr) pairs -------------
__global__ void k_scatter(const int* __restrict__ ei, const float* __restrict__ ea,
                          const int* __restrict__ excl, const int* __restrict__ boff,
                          int* __restrict__ cnt, int* __restrict__ swv,
                          float* __restrict__ awv, int E) {
  int e = blockIdx.x * blockDim.x + threadIdx.x;
  if (e >= E) return;
  int d = ei[E + e];
  int p = excl[d] + boff[d >> 10] + atomicAdd(&cnt[d], 1);
  swv[p] = ei[e];
  awv[p] = ea[e];
}

// ---------------- piecewise-linear edge-encoder table ----------------
__global__ void k_table(const float* __restrict__ W1g, const float* __restrict__ b1g,
                        const float* __restrict__ W2g, const float* __restrict__ b2g,
                        float* __restrict__ tabA, float* __restrict__ tabB,
                        float* __restrict__ tsort) {
  __shared__ float w1[128], b1[128], key[128];
  __shared__ int idx[128];
  __shared__ float w2[128][128];
  const int t = threadIdx.x;  // 128 threads
  w1[t] = W1g[t];
  b1[t] = b1g[t];
  for (int k = 0; k < 128; ++k) w2[k][t] = W2g[k * 128 + t];
  __syncthreads();
  float s0 = w1[t];
  key[t] = (s0 != 0.0f) ? (-b1[t] / s0) : __builtin_inff();
  idx[t] = t;
  for (int size = 2; size <= 128; size <<= 1) {
    for (int stride = size >> 1; stride > 0; stride >>= 1) {
      __syncthreads();
      int p = t ^ stride;
      if (p > t) {
        bool up = ((t & size) == 0);
        float k1 = key[t], k2 = key[p];
        if (up == (k1 > k2)) {
          int i1 = idx[t], i2 = idx[p];
          key[t] = k2; key[p] = k1; idx[t] = i2; idx[p] = i1;
        }
      }
    }
  }
  __syncthreads();
  tsort[t] = key[t];
  float A = 0.0f, B = b2g[t];
  for (int k = 0; k < 128; ++k) {
    float s = w1[k], bb = b1[k], w = w2[k][t];
    if (s < 0.0f) { A = fmaf(s, w, A); B = fmaf(bb, w, B); }
    else if (s == 0.0f && bb > 0.0f) { B = fmaf(bb, w, B); }
  }
  tabA[t] = A;
  tabB[t] = B;
  for (int i = 0; i < 128; ++i) {
    float kv = key[i];
    int kk = idx[i];
    if (kv < __builtin_inff()) {
      float s = w1[kk], bb = b1[kk], w = w2[kk][t];
      if (s > 0.0f) { A = fmaf(s, w, A); B = fmaf(bb, w, B); }
      else { A = fmaf(-s, w, A); B = fmaf(-bb, w, B); }
    }
    tabA[(i + 1) * 128 + t] = A;
    tabB[(i + 1) * 128 + t] = B;
  }
}

// ---- per-edge interval index, packed with src: spk = src | (pos<<20) ----
__global__ __launch_bounds__(256) void k_pos(const int* __restrict__ swv,
                                             const float* __restrict__ awv,
                                             const float* __restrict__ tsort,
                                             int* __restrict__ spk, int E) {
  __shared__ float ts[128];
  if (threadIdx.x < 128) ts[threadIdx.x] = tsort[threadIdx.x];
  __syncthreads();
  int i = blockIdx.x * blockDim.x + threadIdx.x;
  if (i >= E) return;
  float a = awv[i];
  int pos = 0;
#pragma unroll
  for (int st = 64; st > 0; st >>= 1)
    if (pos + st <= 128 && ts[pos + st - 1] < a) pos += st;
  spk[i] = swv[i] | (pos << 20);
}

// -- per-node gather-aggregate: zin[n] = bf16((1+eps)*h[n] + sum relu(...)) --
__global__ __launch_bounds__(256) void k_agg(
    const float* __restrict__ h, const int* __restrict__ spk,
    const float* __restrict__ awv, const int* __restrict__ excl,
    const int* __restrict__ boff, const float* __restrict__ tabA,
    const float* __restrict__ tabB, const float* __restrict__ epsP,
    unsigned* __restrict__ zin, int N, int E) {
  // wave-uniform node index (forces scalar bucket bounds + s_load of edge data)
  int w = __builtin_amdgcn_readfirstlane((int)((blockIdx.x * 256 + threadIdx.x) >> 6));
  if (w >= N) return;
  int lane = threadIdx.x & 63;
  int start = excl[w] + boff[w >> 10];
  int end = (w + 1 < N) ? (excl[w + 1] + boff[(w + 1) >> 10]) : E;
  int j = lane * 2;
  float a0 = 0.0f, a1 = 0.0f, c0 = 0.0f, c1 = 0.0f;
  int i = start;
  for (; i + 2 <= end; i += 2) {
    int sp0 = spk[i], sp1 = spk[i + 1];
    float aa = awv[i], ab = awv[i + 1];
    int s0 = sp0 & 0xFFFFF, p0 = sp0 >> 20;
    int s1 = sp1 & 0xFFFFF, p1 = sp1 >> 20;
    float2 h0 = *(const float2*)(h + (size_t)s0 * HID + j);
    float2 A0 = *(const float2*)(tabA + (size_t)p0 * HID + j);
    float2 B0 = *(const float2*)(tabB + (size_t)p0 * HID + j);
    float2 h1 = *(const float2*)(h + (size_t)s1 * HID + j);
    float2 A1 = *(const float2*)(tabA + (size_t)p1 * HID + j);
    float2 B1 = *(const float2*)(tabB + (size_t)p1 * HID + j);
    a0 += fmaxf(h0.x + fmaf(A0.x, aa, B0.x), 0.0f);
    a1 += fmaxf(h0.y + fmaf(A0.y, aa, B0.y), 0.0f);
    c0 += fmaxf(h1.x + fmaf(A1.x, ab, B1.x), 0.0f);
    c1 += fmaxf(h1.y + fmaf(A1.y, ab, B1.y), 0.0f);
  }
  if (i < end) {
    int sp0 = spk[i];
    float aa = awv[i];
    int s0 = sp0 & 0xFFFFF, p0 = sp0 >> 20;
    float2 h0 = *(const float2*)(h + (size_t)s0 * HID + j);
    float2 A0 = *(const float2*)(tabA + (size_t)p0 * HID + j);
    float2 B0 = *(const float2*)(tabB + (size_t)p0 * HID + j);
    a0 += fmaxf(h0.x + fmaf(A0.x, aa, B0.x), 0.0f);
    a1 += fmaxf(h0.y + fmaf(A0.y, aa, B0.y), 0.0f);
  }
  a0 += c0;
  a1 += c1;
  float ep1 = 1.0f + *epsP;
  float2 hn = *(const float2*)(h + (size_t)w * HID + j);
  float ox = fmaf(ep1, hn.x, a0);
  float oy = fmaf(ep1, hn.y, a1);
  zin[(size_t)w * 64 + lane] = (unsigned)bf16rne(ox) | ((unsigned)bf16rne(oy) << 16);
}

// ------------- weight pack into B-fragment layout (bf16) -------------
__device__ __forceinline__ void pack_one(const float* __restrict__ W, int K, int M,
                                         int t, unsigned short* __restrict__ out) {
  int lane = t & 63, f = t >> 6;
  int KS = K >> 5;
  int mt = f / KS, ks = f - mt * KS;
  int col = mt * 16 + (lane & 15);
  int kb = ks * 32 + ((lane >> 4) * 8);
  unsigned r0, r1, r2, r3;
  r0 = bf16rne(W[(size_t)(kb + 0) * M + col]) | ((unsigned)bf16rne(W[(size_t)(kb + 1) * M + col]) << 16);
  r1 = bf16rne(W[(size_t)(kb + 2) * M + col]) | ((unsigned)bf16rne(W[(size_t)(kb + 3) * M + col]) << 16);
  r2 = bf16rne(W[(size_t)(kb + 4) * M + col]) | ((unsigned)bf16rne(W[(size_t)(kb + 5) * M + col]) << 16);
  r3 = bf16rne(W[(size_t)(kb + 6) * M + col]) | ((unsigned)bf16rne(W[(size_t)(kb + 7) * M + col]) << 16);
  uint4 v = make_uint4(r0, r1, r2, r3);
  *(uint4*)(out + ((size_t)f * 64 + lane) * 8) = v;
}

__global__ __launch_bounds__(256) void k_pack(
    const float* __restrict__ lin_W, const float* __restrict__ m1_W,
    const float* __restrict__ m2_W, unsigned short* __restrict__ pk_lin,
    unsigned short* __restrict__ pk_m1, unsigned short* __restrict__ pk_m2) {
  int t = blockIdx.x * 256 + threadIdx.x;
  if (t < 2048) {
    pack_one(lin_W, 128, 128, t, pk_lin);
  } else if (t < 10240) {
    int u = t - 2048;
    int l = u >> 12;
    pack_one(m1_W + (size_t)l * 128 * 256, 128, 256, u & 4095, pk_m1 + (size_t)l * 32768);
  } else if (t < 18432) {
    int u = t - 10240;
    int l = u >> 12;
    pack_one(m2_W + (size_t)l * 256 * 128, 256, 128, u & 4095, pk_m2 + (size_t)l * 32768);
  }
}

// ---------------- MFMA skinny GEMM: out = pre(in) @ W + bias ----------------
// MODE 0: in fp32 x; epilogue agg_edge(last_dst/last_src, enc) -> fp32 h
// MODE 1: in bf16 zin (direct A-frags); out bf16 z2 + BN partials (LDS reduce)
// MODE 2: in bf16 z2, pre-op relu(z*scale+shift); out fp32 (+optional relu)
template <int K, int M, int MODE, bool RELU_OUT>
__global__ __launch_bounds__(256) void k_mgemm(
    const void* __restrict__ in0, const unsigned short* __restrict__ pkW,
    const float* __restrict__ bias, void* __restrict__ outv,
    const float* __restrict__ pre_a, const float* __restrict__ pre_b,
    float* __restrict__ pS1, float* __restrict__ pS2,
    const int* __restrict__ last_dst, const int* __restrict__ last_src,
    const float* __restrict__ ea, const float* __restrict__ encW,
    const float* __restrict__ encb) {
  constexpr int KS = K / 32, MT = M / 16;
  __shared__ float red[(MODE == 1) ? 2048 : 1];  // [2][4 waves][256 cols]
  const int t = threadIdx.x;
  const int w = t >> 6, lane = t & 63;
  const int row0 = blockIdx.x * 64 + w * 16;
  const int arow = row0 + (lane & 15);
  const int rg = arow < N_NODES ? arow : N_NODES - 1;
  const int kb = (lane >> 4) * 8;

  short8v afrag[KS];
#pragma unroll
  for (int ks = 0; ks < KS; ++ks) {
    const int k0 = ks * 32 + kb;
    if (MODE == 0) {
      const float* in = (const float*)in0;
      float4 v0 = *(const float4*)(in + (size_t)rg * K + k0);
      float4 v1 = *(const float4*)(in + (size_t)rg * K + k0 + 4);
      short8v a;
      a[0] = (short)bf16rne(v0.x); a[1] = (short)bf16rne(v0.y);
      a[2] = (short)bf16rne(v0.z); a[3] = (short)bf16rne(v0.w);
      a[4] = (short)bf16rne(v1.x); a[5] = (short)bf16rne(v1.y);
      a[6] = (short)bf16rne(v1.z); a[7] = (short)bf16rne(v1.w);
      afrag[ks] = a;
    } else if (MODE == 1) {
      afrag[ks] = *(const short8v*)((const unsigned short*)in0 + (size_t)rg * K + k0);
    } else {
      short8v raw = *(const short8v*)((const unsigned short*)in0 + (size_t)rg * K + k0);
      float4 sa0 = *(const float4*)(pre_a + k0);
      float4 sa1 = *(const float4*)(pre_a + k0 + 4);
      float4 sb0 = *(const float4*)(pre_b + k0);
      float4 sb1 = *(const float4*)(pre_b + k0 + 4);
      short8v a;
      a[0] = (short)bf16rne(fmaxf(fmaf(bf16tof((unsigned short)raw[0]), sa0.x, sb0.x), 0.0f));
      a[1] = (short)bf16rne(fmaxf(fmaf(bf16tof((unsigned short)raw[1]), sa0.y, sb0.y), 0.0f));
      a[2] = (short)bf16rne(fmaxf(fmaf(bf16tof((unsigned short)raw[2]), sa0.z, sb0.z), 0.0f));
      a[3] = (short)bf16rne(fmaxf(fmaf(bf16tof((unsigned short)raw[3]), sa0.w, sb0.w), 0.0f));
      a[4] = (short)bf16rne(fmaxf(fmaf(bf16tof((unsigned short)raw[4]), sa1.x, sb1.x), 0.0f));
      a[5] = (short)bf16rne(fmaxf(fmaf(bf16tof((unsigned short)raw[5]), sa1.y, sb1.y), 0.0f));
      a[6] = (short)bf16rne(fmaxf(fmaf(bf16tof((unsigned short)raw[6]), sa1.z, sb1.z), 0.0f));
      a[7] = (short)bf16rne(fmaxf(fmaf(bf16tof((unsigned short)raw[7]), sa1.w, sb1.w), 0.0f));
      afrag[ks] = a;
    }
  }

  f32x4 acc[MT];
#pragma unroll
  for (int mt = 0; mt < MT; ++mt) acc[mt] = (f32x4){0.f, 0.f, 0.f, 0.f};
#pragma unroll
  for (int mt = 0; mt < MT; ++mt) {
#pragma unroll
    for (int ks = 0; ks < KS; ++ks) {
      short8v bfrag = *(const short8v*)(pkW + ((size_t)(mt * KS + ks) * 64 + lane) * 8);
      acc[mt] = __builtin_amdgcn_mfma_f32_16x16x32_bf16(afrag[ks], bfrag, acc[mt], 0, 0, 0);
    }
  }

  // epilogue: C/D layout col = lane&15, row = (lane>>4)*4 + reg
  const int colb = lane & 15;
  const int rbase = row0 + (lane >> 4) * 4;
#pragma unroll
  for (int mt = 0; mt < MT; ++mt) {
    const int col = mt * 16 + colb;
    const float b = bias[col];
    if (MODE == 1) {
      unsigned short* out = (unsigned short*)outv;
      float s1 = 0.0f, s2 = 0.0f;
#pragma unroll
      for (int r = 0; r < 4; ++r) {
        int R = rbase + r;
        if (R < N_NODES) {
          float v = acc[mt][r] + b;
          out[(size_t)R * M + col] = bf16rne(v);
          s1 += v;
          s2 = fmaf(v, v, s2);
        }
      }
      s1 += __shfl_xor(s1, 16);
      s1 += __shfl_xor(s1, 32);
      s2 += __shfl_xor(s2, 16);
      s2 += __shfl_xor(s2, 32);
      if (lane < 16) {
        red[w * 256 + col] = s1;
        red[1024 + w * 256 + col] = s2;
      }
    } else if (MODE == 2) {
      float* out = (float*)outv;
#pragma unroll
      for (int r = 0; r < 4; ++r) {
        int R = rbase + r;
        if (R < N_NODES) {
          float v = acc[mt][r] + b;
          if (RELU_OUT) v = fmaxf(v, 0.0f);
          out[(size_t)R * M + col] = v;
        }
      }
    } else {
      float* out = (float*)outv;
      const float ew = encW[col], eb = encb[col];
#pragma unroll
      for (int r = 0; r < 4; ++r) {
        int R = rbase + r;
        if (R < N_NODES) {
          float v = acc[mt][r] + b;
          int ld = last_dst[R];
          int ls = last_src[R];
          int e = (ld >= 0) ? ld : ls;  // dst assignment overwrites src assignment
          if (e >= 0) v = fmaxf(v + fmaf(ea[e], ew, eb), 0.0f);
          out[(size_t)R * M + col] = v;
        }
      }
    }
  }
  if (MODE == 1) {
    __syncthreads();
    if (t < 256) {
      float a = red[t] + red[256 + t] + red[512 + t] + red[768 + t];
      float q = red[1024 + t] + red[1280 + t] + red[1536 + t] + red[1792 + t];
      pS1[(size_t)blockIdx.x * 256 + t] = a;
      pS2[(size_t)blockIdx.x * 256 + t] = q;
    }
  }
}

// ------- BN finalize stage 1: 64 blocks reduce 1563 partials -> 64 partials -------
__global__ __launch_bounds__(256) void k_bnred(
    const float* __restrict__ pS1, const float* __restrict__ pS2,
    float* __restrict__ qS1, float* __restrict__ qS2, int nblk) {
  int j = threadIdx.x;  // 256
  int b = blockIdx.x;   // 64
  float s1 = 0.0f, s2 = 0.0f;
  for (int i = b; i < nblk; i += 64) {
    s1 += pS1[(size_t)i * 256 + j];
    s2 += pS2[(size_t)i * 256 + j];
  }
  qS1[b * 256 + j] = s1;
  qS2[b * 256 + j] = s2;
}

// ------- BN finalize stage 2: fold 64 partials, emit scale/shift -------
__global__ __launch_bounds__(256) void k_bnfin2(
    const float* __restrict__ qS1, const float* __restrict__ qS2,
    const float* __restrict__ g, const float* __restrict__ bb,
    float* __restrict__ scale, float* __restrict__ shift) {
  int j = threadIdx.x;  // 256
  float s1 = 0.0f, s2 = 0.0f;
#pragma unroll 8
  for (int i = 0; i < 64; ++i) {
    s1 += qS1[i * 256 + j];
    s2 += qS2[i * 256 + j];
  }
  const float inv = 1.0f / (float)N_NODES;
  float mu = s1 * inv;
  float var = s2 * inv - mu * mu;
  float sc = g[j] * rsqrtf(var + 1e-5f);
  scale[j] = sc;
  shift[j] = fmaf(-mu, sc, bb[j]);
}

extern "C" void kernel_launch(void* const* d_in, const int* in_sizes, int n_in,
                              void* d_out, int out_size, void* d_ws, size_t ws_size,
                              hipStream_t stream) {
  const float* x     = (const float*)d_in[0];
  const int*   ei    = (const int*)d_in[1];
  const float* ea    = (const float*)d_in[2];
  const float* lin_W = (const float*)d_in[3];
  const float* lin_b = (const float*)d_in[4];
  const float* enc_W = (const float*)d_in[5];
  const float* enc_b = (const float*)d_in[6];
  const float* eps   = (const float*)d_in[7];
  const float* e1_W  = (const float*)d_in[8];
  const float* e1_b  = (const float*)d_in[9];
  const float* e2_W  = (const float*)d_in[10];
  const float* e2_b  = (const float*)d_in[11];
  const float* m1_W  = (const float*)d_in[12];
  const float* m1_b  = (const float*)d_in[13];
  const float* bn_g  = (const float*)d_in[14];
  const float* bn_b  = (const float*)d_in[15];
  const float* m2_W  = (const float*)d_in[16];
  const float* m2_b  = (const float*)d_in[17];
  float* hbuf = (float*)d_out;  // h lives in d_out; final GEMM2 overwrites it

  const int NB_SCAN = (N_NODES + 1023) / 1024;  // 98
  const int NB_GEMM = (N_NODES + 63) / 64;      // 1563

  float* ws = (float*)d_ws;
  size_t o = 0;
  unsigned* zin_u = (unsigned*)(ws + o);          o += (size_t)N_NODES * 64;   // bf16 zin
  unsigned short* z2_u = (unsigned short*)(ws + o); o += (size_t)N_NODES * 128; // bf16 z2
  int* last_dst = (int*)(ws + o);  o += N_NODES;
  int* last_src = (int*)(ws + o);  o += N_NODES;
  int* deg = (int*)(ws + o);       o += N_NODES;
  int* cnt = (int*)(ws + o);       o += N_NODES;
  int* excl = (int*)(ws + o);      o += N_NODES;
  int* bsum = (int*)(ws + o);      o += 128;
  int* boff = (int*)(ws + o);      o += 128;
  int* swv = (int*)(ws + o);       o += E_EDGES;
  float* awv = ws + o;             o += E_EDGES;
  int* spk = (int*)(ws + o);       o += E_EDGES;
  float* tabA = ws + o;            o += 129 * 128;
  float* tabB = ws + o;            o += 129 * 128;
  float* tsort = ws + o;           o += 128;
  float* pS1 = ws + o;             o += (size_t)NB_GEMM * 256;
  float* pS2 = ws + o;             o += (size_t)NB_GEMM * 256;
  float* qS1 = ws + o;             o += 64 * 256;
  float* qS2 = ws + o;             o += 64 * 256;
  float* scale = ws + o;           o += 256;
  float* shift = ws + o;           o += 256;
  unsigned short* pk_lin = (unsigned short*)(ws + o); o += 8192;   // 16384 bf16
  unsigned short* pk_m1  = (unsigned short*)(ws + o); o += 32768;  // 2 x 32768 bf16
  unsigned short* pk_m2  = (unsigned short*)(ws + o); o += 32768;  // 2 x 32768 bf16
  if (ws_size < o * sizeof(float)) return;

  hipMemsetAsync(last_dst, 0xFF, 2 * (size_t)N_NODES * sizeof(int), stream);
  hipMemsetAsync(deg, 0, 2 * (size_t)N_NODES * sizeof(int), stream);  // deg + cnt
  k_last<<<(E_EDGES + 255) / 256, 256, 0, stream>>>(ei, last_src, last_dst, deg, E_EDGES);
  k_scan1<<<NB_SCAN, 256, 0, stream>>>(deg, excl, bsum, N_NODES);
  k_scan2<<<1, 128, 0, stream>>>(bsum, boff, NB_SCAN);
  k_scatter<<<(E_EDGES + 255) / 256, 256, 0, stream>>>(ei, ea, excl, boff, cnt, swv, awv, E_EDGES);
  k_pack<<<72, 256, 0, stream>>>(lin_W, m1_W, m2_W, pk_lin, pk_m1, pk_m2);

  // h = x @ lin_W + lin_b, then agg_edge epilogue
  k_mgemm<128, 128, 0, false><<<NB_GEMM, 256, 0, stream>>>(
      x, pk_lin, lin_b, hbuf, nullptr, nullptr, nullptr, nullptr,
      last_dst, last_src, ea, enc_W, enc_b);

  for (int l = 0; l < 2; ++l) {
    k_table<<<1, 128, 0, stream>>>(e1_W + l * 128, e1_b + l * 128,
                                   e2_W + l * 128 * 128, e2_b + l * 128,
                                   tabA, tabB, tsort);
    k_pos<<<(E_EDGES + 255) / 256, 256, 0, stream>>>(swv, awv, tsort, spk, E_EDGES);
    k_agg<<<(N_NODES * 64 + 255) / 256, 256, 0, stream>>>(
        hbuf, spk, awv, excl, boff, tabA, tabB, eps + l, zin_u, N_NODES, E_EDGES);
    k_mgemm<128, 256, 1, false><<<NB_GEMM, 256, 0, stream>>>(
        zin_u, pk_m1 + (size_t)l * 32768, m1_b + l * 256, z2_u, nullptr, nullptr,
        pS1, pS2, nullptr, nullptr, nullptr, nullptr, nullptr);
    k_bnred<<<64, 256, 0, stream>>>(pS1, pS2, qS1, qS2, NB_GEMM);
    k_bnfin2<<<1, 256, 0, stream>>>(qS1, qS2, bn_g + l * 256, bn_b + l * 256,
                                    scale, shift);
    if (l == 0) {
      k_mgemm<256, 128, 2, true><<<NB_GEMM, 256, 0, stream>>>(
          z2_u, pk_m2 + (size_t)l * 32768, m2_b + l * 128, hbuf, scale, shift,
          nullptr, nullptr, nullptr, nullptr, nullptr, nullptr, nullptr);
    } else {
      k_mgemm<256, 128, 2, false><<<NB_GEMM, 256, 0, stream>>>(
          z2_u, pk_m2 + (size_t)l * 32768, m2_b + l * 128, hbuf, scale, shift,
          nullptr, nullptr, nullptr, nullptr, nullptr, nullptr, nullptr);
    }
  }
}

// Round 9
// 642.595 us; speedup vs baseline: 2.6555x; 1.0689x over previous
//
#include <hip/hip_runtime.h>

#define N_NODES 100000
#define E_EDGES 600000
#define HID 128

typedef __attribute__((ext_vector_type(8))) short short8v;
typedef __attribute__((ext_vector_type(4))) float f32x4;

__device__ __forceinline__ unsigned short bf16rne(float x) {
  unsigned u = __float_as_uint(x);
  return (unsigned short)((u + 0x7FFFu + ((u >> 16) & 1u)) >> 16);
}
__device__ __forceinline__ float bf16tof(unsigned short u) {
  return __uint_as_float(((unsigned)u) << 16);
}

// ------------- last-edge (last-write-wins) + dst-degree histogram -------------
__global__ void k_last(const int* __restrict__ ei, int* __restrict__ last_src,
                       int* __restrict__ last_dst, int* __restrict__ deg, int E) {
  int e = blockIdx.x * blockDim.x + threadIdx.x;
  if (e >= E) return;
  int s = ei[e], d = ei[E + e];
  atomicMax(&last_src[s], e);
  atomicMax(&last_dst[d], e);
  atomicAdd(&deg[d], 1);
}

// ------------- 2-level exclusive scan over deg (CSR row offsets) -------------
__global__ __launch_bounds__(256) void k_scan1(const int* __restrict__ deg,
                                               int* __restrict__ excl,
                                               int* __restrict__ bsum, int n) {
  __shared__ int sh[256];
  int b = blockIdx.x, t = threadIdx.x;
  int i0 = b * 1024 + t * 4;
  int v0 = (i0 + 0 < n) ? deg[i0 + 0] : 0;
  int v1 = (i0 + 1 < n) ? deg[i0 + 1] : 0;
  int v2 = (i0 + 2 < n) ? deg[i0 + 2] : 0;
  int v3 = (i0 + 3 < n) ? deg[i0 + 3] : 0;
  int tsum = v0 + v1 + v2 + v3;
  sh[t] = tsum;
  __syncthreads();
  for (int off = 1; off < 256; off <<= 1) {
    int add = (t >= off) ? sh[t - off] : 0;
    __syncthreads();
    sh[t] += add;
    __syncthreads();
  }
  int ex = sh[t] - tsum;
  if (i0 + 0 < n) excl[i0 + 0] = ex;
  if (i0 + 1 < n) excl[i0 + 1] = ex + v0;
  if (i0 + 2 < n) excl[i0 + 2] = ex + v0 + v1;
  if (i0 + 3 < n) excl[i0 + 3] = ex + v0 + v1 + v2;
  if (t == 255) bsum[b] = sh[255];
}

__global__ void k_scan2(const int* __restrict__ bsum, int* __restrict__ boff, int nb) {
  __shared__ int sh[128];
  int t = threadIdx.x;
  int v = (t < nb) ? bsum[t] : 0;
  sh[t] = v;
  __syncthreads();
  for (int off = 1; off < 128; off <<= 1) {
    int add = (t >= off) ? sh[t - off] : 0;
    __syncthreads();
    sh[t] += add;
    __syncthreads();
  }
  if (t < nb) boff[t] = sh[t] - v;
}

// ------- scatter edges into dst buckets: one int2 (src, attr_bits) record -------
__global__ void k_scatter(const int* __restrict__ ei, const float* __restrict__ ea,
                          const int* __restrict__ excl, const int* __restrict__ boff,
                          int* __restrict__ cnt, int2* __restrict__ pairE, int E) {
  int e = blockIdx.x * blockDim.x + threadIdx.x;
  if (e >= E) return;
  int d = ei[E + e];
  int p = excl[d] + boff[d >> 10] + atomicAdd(&cnt[d], 1);
  pairE[p] = make_int2(ei[e], __float_as_int(ea[e]));
}

// ---------------- piecewise-linear edge-encoder table (both layers) ----------------
__global__ void k_table(const float* __restrict__ e1_W, const float* __restrict__ e1_b,
                        const float* __restrict__ e2_W, const float* __restrict__ e2_b,
                        float* __restrict__ tabA, float* __restrict__ tabB,
                        float* __restrict__ tsort) {
  const int l = blockIdx.x;  // layer
  const float* W1g = e1_W + l * 128;
  const float* b1g = e1_b + l * 128;
  const float* W2g = e2_W + l * 128 * 128;
  const float* b2g = e2_b + l * 128;
  float* tA = tabA + (size_t)l * 129 * 128;
  float* tB = tabB + (size_t)l * 129 * 128;
  float* tS = tsort + l * 128;
  __shared__ float w1[128], b1[128], key[128];
  __shared__ int idx[128];
  __shared__ float w2[128][128];
  const int t = threadIdx.x;  // 128 threads
  w1[t] = W1g[t];
  b1[t] = b1g[t];
  for (int k = 0; k < 128; ++k) w2[k][t] = W2g[k * 128 + t];
  __syncthreads();
  float s0 = w1[t];
  key[t] = (s0 != 0.0f) ? (-b1[t] / s0) : __builtin_inff();
  idx[t] = t;
  for (int size = 2; size <= 128; size <<= 1) {
    for (int stride = size >> 1; stride > 0; stride >>= 1) {
      __syncthreads();
      int p = t ^ stride;
      if (p > t) {
        bool up = ((t & size) == 0);
        float k1 = key[t], k2 = key[p];
        if (up == (k1 > k2)) {
          int i1 = idx[t], i2 = idx[p];
          key[t] = k2; key[p] = k1; idx[t] = i2; idx[p] = i1;
        }
      }
    }
  }
  __syncthreads();
  tS[t] = key[t];
  float A = 0.0f, B = b2g[t];
  for (int k = 0; k < 128; ++k) {
    float s = w1[k], bb = b1[k], w = w2[k][t];
    if (s < 0.0f) { A = fmaf(s, w, A); B = fmaf(bb, w, B); }
    else if (s == 0.0f && bb > 0.0f) { B = fmaf(bb, w, B); }
  }
  tA[t] = A;
  tB[t] = B;
  for (int i = 0; i < 128; ++i) {
    float kv = key[i];
    int kk = idx[i];
    if (kv < __builtin_inff()) {
      float s = w1[kk], bb = b1[kk], w = w2[kk][t];
      if (s > 0.0f) { A = fmaf(s, w, A); B = fmaf(bb, w, B); }
      else { A = fmaf(-s, w, A); B = fmaf(-bb, w, B); }
    }
    tA[(i + 1) * 128 + t] = A;
    tB[(i + 1) * 128 + t] = B;
  }
}

// ---- per-edge interval indices for BOTH layers in one pass over bucket order ----
__global__ __launch_bounds__(256) void k_pos(const int2* __restrict__ pairE,
                                             const float* __restrict__ tsort,
                                             unsigned char* __restrict__ posb0,
                                             unsigned char* __restrict__ posb1, int E) {
  __shared__ float ts0[128], ts1[128];
  if (threadIdx.x < 128) {
    ts0[threadIdx.x] = tsort[threadIdx.x];
    ts1[threadIdx.x] = tsort[128 + threadIdx.x];
  }
  __syncthreads();
  int i = blockIdx.x * blockDim.x + threadIdx.x;
  if (i >= E) return;
  float a = __int_as_float(pairE[i].y);
  int p0 = 0, p1 = 0;
#pragma unroll
  for (int st = 64; st > 0; st >>= 1) {
    if (p0 + st <= 128 && ts0[p0 + st - 1] < a) p0 += st;
    if (p1 + st <= 128 && ts1[p1 + st - 1] < a) p1 += st;
  }
  posb0[i] = (unsigned char)p0;
  posb1[i] = (unsigned char)p1;
}

// -- per-node gather-aggregate (bf16 h): zin[n] = bf16((1+eps)*h[n] + sum relu) --
__global__ __launch_bounds__(256) void k_agg(
    const unsigned short* __restrict__ h, const int2* __restrict__ pairE,
    const unsigned char* __restrict__ posb, const int* __restrict__ excl,
    const int* __restrict__ boff, const float* __restrict__ tabA,
    const float* __restrict__ tabB, const float* __restrict__ epsP,
    unsigned* __restrict__ zin, int N, int E) {
  // wave-uniform node index (forces scalar bucket bounds + s_load of edge data)
  int w = __builtin_amdgcn_readfirstlane((int)((blockIdx.x * 256 + threadIdx.x) >> 6));
  if (w >= N) return;
  int lane = threadIdx.x & 63;
  int start = excl[w] + boff[w >> 10];
  int end = (w + 1 < N) ? (excl[w + 1] + boff[(w + 1) >> 10]) : E;
  int j = lane * 2;
  float a0 = 0.0f, a1 = 0.0f, c0 = 0.0f, c1 = 0.0f;
  int i = start;
  for (; i + 2 <= end; i += 2) {
    int2 pr0 = pairE[i], pr1 = pairE[i + 1];
    int p0 = posb[i], p1 = posb[i + 1];
    float aa = __int_as_float(pr0.y), ab = __int_as_float(pr1.y);
    unsigned hv0 = *(const unsigned*)(h + (size_t)pr0.x * HID + j);
    float2 A0 = *(const float2*)(tabA + (size_t)p0 * HID + j);
    float2 B0 = *(const float2*)(tabB + (size_t)p0 * HID + j);
    unsigned hv1 = *(const unsigned*)(h + (size_t)pr1.x * HID + j);
    float2 A1 = *(const float2*)(tabA + (size_t)p1 * HID + j);
    float2 B1 = *(const float2*)(tabB + (size_t)p1 * HID + j);
    a0 += fmaxf(__uint_as_float(hv0 << 16) + fmaf(A0.x, aa, B0.x), 0.0f);
    a1 += fmaxf(__uint_as_float(hv0 & 0xFFFF0000u) + fmaf(A0.y, aa, B0.y), 0.0f);
    c0 += fmaxf(__uint_as_float(hv1 << 16) + fmaf(A1.x, ab, B1.x), 0.0f);
    c1 += fmaxf(__uint_as_float(hv1 & 0xFFFF0000u) + fmaf(A1.y, ab, B1.y), 0.0f);
  }
  if (i < end) {
    int2 pr0 = pairE[i];
    int p0 = posb[i];
    float aa = __int_as_float(pr0.y);
    unsigned hv0 = *(const unsigned*)(h + (size_t)pr0.x * HID + j);
    float2 A0 = *(const float2*)(tabA + (size_t)p0 * HID + j);
    float2 B0 = *(const float2*)(tabB + (size_t)p0 * HID + j);
    a0 += fmaxf(__uint_as_float(hv0 << 16) + fmaf(A0.x, aa, B0.x), 0.0f);
    a1 += fmaxf(__uint_as_float(hv0 & 0xFFFF0000u) + fmaf(A0.y, aa, B0.y), 0.0f);
  }
  a0 += c0;
  a1 += c1;
  float ep1 = 1.0f + *epsP;
  unsigned hn = *(const unsigned*)(h + (size_t)w * HID + j);
  float ox = fmaf(ep1, __uint_as_float(hn << 16), a0);
  float oy = fmaf(ep1, __uint_as_float(hn & 0xFFFF0000u), a1);
  zin[(size_t)w * 64 + lane] = (unsigned)bf16rne(ox) | ((unsigned)bf16rne(oy) << 16);
}

// ------------- weight pack into B-fragment layout (bf16) -------------
__device__ __forceinline__ void pack_one(const float* __restrict__ W, int K, int M,
                                         int t, unsigned short* __restrict__ out) {
  int lane = t & 63, f = t >> 6;
  int KS = K >> 5;
  int mt = f / KS, ks = f - mt * KS;
  int col = mt * 16 + (lane & 15);
  int kb = ks * 32 + ((lane >> 4) * 8);
  unsigned r0, r1, r2, r3;
  r0 = bf16rne(W[(size_t)(kb + 0) * M + col]) | ((unsigned)bf16rne(W[(size_t)(kb + 1) * M + col]) << 16);
  r1 = bf16rne(W[(size_t)(kb + 2) * M + col]) | ((unsigned)bf16rne(W[(size_t)(kb + 3) * M + col]) << 16);
  r2 = bf16rne(W[(size_t)(kb + 4) * M + col]) | ((unsigned)bf16rne(W[(size_t)(kb + 5) * M + col]) << 16);
  r3 = bf16rne(W[(size_t)(kb + 6) * M + col]) | ((unsigned)bf16rne(W[(size_t)(kb + 7) * M + col]) << 16);
  uint4 v = make_uint4(r0, r1, r2, r3);
  *(uint4*)(out + ((size_t)f * 64 + lane) * 8) = v;
}

__global__ __launch_bounds__(256) void k_pack(
    const float* __restrict__ lin_W, const float* __restrict__ m1_W,
    const float* __restrict__ m2_W, unsigned short* __restrict__ pk_lin,
    unsigned short* __restrict__ pk_m1, unsigned short* __restrict__ pk_m2) {
  int t = blockIdx.x * 256 + threadIdx.x;
  if (t < 2048) {
    pack_one(lin_W, 128, 128, t, pk_lin);
  } else if (t < 10240) {
    int u = t - 2048;
    int l = u >> 12;
    pack_one(m1_W + (size_t)l * 128 * 256, 128, 256, u & 4095, pk_m1 + (size_t)l * 32768);
  } else if (t < 18432) {
    int u = t - 10240;
    int l = u >> 12;
    pack_one(m2_W + (size_t)l * 256 * 128, 256, 128, u & 4095, pk_m2 + (size_t)l * 32768);
  }
}

// ---------------- MFMA skinny GEMM: out = pre(in) @ W + bias ----------------
// MODE 0: in fp32 x; epilogue agg_edge(last_dst/last_src, enc) -> bf16 h
// MODE 1: in bf16 zin (direct A-frags); out bf16 z2 + BN partials (LDS reduce)
// MODE 2: in bf16 z2, pre-op relu(z*scale+shift); out bf16 h (OBF) or fp32 d_out
template <int K, int M, int MODE, bool RELU_OUT, bool OBF>
__global__ __launch_bounds__(256) void k_mgemm(
    const void* __restrict__ in0, const unsigned short* __restrict__ pkW,
    const float* __restrict__ bias, void* __restrict__ outv,
    const float* __restrict__ pre_a, const float* __restrict__ pre_b,
    float* __restrict__ pS1, float* __restrict__ pS2,
    const int* __restrict__ last_dst, const int* __restrict__ last_src,
    const float* __restrict__ ea, const float* __restrict__ encW,
    const float* __restrict__ encb) {
  constexpr int KS = K / 32, MT = M / 16;
  __shared__ float red[(MODE == 1) ? 2048 : 1];  // [2][4 waves][256 cols]
  const int t = threadIdx.x;
  const int w = t >> 6, lane = t & 63;
  const int row0 = blockIdx.x * 64 + w * 16;
  const int arow = row0 + (lane & 15);
  const int rg = arow < N_NODES ? arow : N_NODES - 1;
  const int kb = (lane >> 4) * 8;

  short8v afrag[KS];
#pragma unroll
  for (int ks = 0; ks < KS; ++ks) {
    const int k0 = ks * 32 + kb;
    if (MODE == 0) {
      const float* in = (const float*)in0;
      float4 v0 = *(const float4*)(in + (size_t)rg * K + k0);
      float4 v1 = *(const float4*)(in + (size_t)rg * K + k0 + 4);
      short8v a;
      a[0] = (short)bf16rne(v0.x); a[1] = (short)bf16rne(v0.y);
      a[2] = (short)bf16rne(v0.z); a[3] = (short)bf16rne(v0.w);
      a[4] = (short)bf16rne(v1.x); a[5] = (short)bf16rne(v1.y);
      a[6] = (short)bf16rne(v1.z); a[7] = (short)bf16rne(v1.w);
      afrag[ks] = a;
    } else if (MODE == 1) {
      afrag[ks] = *(const short8v*)((const unsigned short*)in0 + (size_t)rg * K + k0);
    } else {
      short8v raw = *(const short8v*)((const unsigned short*)in0 + (size_t)rg * K + k0);
      float4 sa0 = *(const float4*)(pre_a + k0);
      float4 sa1 = *(const float4*)(pre_a + k0 + 4);
      float4 sb0 = *(const float4*)(pre_b + k0);
      float4 sb1 = *(const float4*)(pre_b + k0 + 4);
      short8v a;
      a[0] = (short)bf16rne(fmaxf(fmaf(bf16tof((unsigned short)raw[0]), sa0.x, sb0.x), 0.0f));
      a[1] = (short)bf16rne(fmaxf(fmaf(bf16tof((unsigned short)raw[1]), sa0.y, sb0.y), 0.0f));
      a[2] = (short)bf16rne(fmaxf(fmaf(bf16tof((unsigned short)raw[2]), sa0.z, sb0.z), 0.0f));
      a[3] = (short)bf16rne(fmaxf(fmaf(bf16tof((unsigned short)raw[3]), sa0.w, sb0.w), 0.0f));
      a[4] = (short)bf16rne(fmaxf(fmaf(bf16tof((unsigned short)raw[4]), sa1.x, sb1.x), 0.0f));
      a[5] = (short)bf16rne(fmaxf(fmaf(bf16tof((unsigned short)raw[5]), sa1.y, sb1.y), 0.0f));
      a[6] = (short)bf16rne(fmaxf(fmaf(bf16tof((unsigned short)raw[6]), sa1.z, sb1.z), 0.0f));
      a[7] = (short)bf16rne(fmaxf(fmaf(bf16tof((unsigned short)raw[7]), sa1.w, sb1.w), 0.0f));
      afrag[ks] = a;
    }
  }

  f32x4 acc[MT];
#pragma unroll
  for (int mt = 0; mt < MT; ++mt) acc[mt] = (f32x4){0.f, 0.f, 0.f, 0.f};
#pragma unroll
  for (int mt = 0; mt < MT; ++mt) {
#pragma unroll
    for (int ks = 0; ks < KS; ++ks) {
      short8v bfrag = *(const short8v*)(pkW + ((size_t)(mt * KS + ks) * 64 + lane) * 8);
      acc[mt] = __builtin_amdgcn_mfma_f32_16x16x32_bf16(afrag[ks], bfrag, acc[mt], 0, 0, 0);
    }
  }

  // epilogue: C/D layout col = lane&15, row = (lane>>4)*4 + reg
  const int colb = lane & 15;
  const int rbase = row0 + (lane >> 4) * 4;
#pragma unroll
  for (int mt = 0; mt < MT; ++mt) {
    const int col = mt * 16 + colb;
    const float b = bias[col];
    if (MODE == 1) {
      unsigned short* out = (unsigned short*)outv;
      float s1 = 0.0f, s2 = 0.0f;
#pragma unroll
      for (int r = 0; r < 4; ++r) {
        int R = rbase + r;
        if (R < N_NODES) {
          float v = acc[mt][r] + b;
          out[(size_t)R * M + col] = bf16rne(v);
          s1 += v;
          s2 = fmaf(v, v, s2);
        }
      }
      s1 += __shfl_xor(s1, 16);
      s1 += __shfl_xor(s1, 32);
      s2 += __shfl_xor(s2, 16);
      s2 += __shfl_xor(s2, 32);
      if (lane < 16) {
        red[w * 256 + col] = s1;
        red[1024 + w * 256 + col] = s2;
      }
    } else if (MODE == 2) {
#pragma unroll
      for (int r = 0; r < 4; ++r) {
        int R = rbase + r;
        if (R < N_NODES) {
          float v = acc[mt][r] + b;
          if (RELU_OUT) v = fmaxf(v, 0.0f);
          if (OBF) ((unsigned short*)outv)[(size_t)R * M + col] = bf16rne(v);
          else ((float*)outv)[(size_t)R * M + col] = v;
        }
      }
    } else {
      const float ew = encW[col], eb = encb[col];
#pragma unroll
      for (int r = 0; r < 4; ++r) {
        int R = rbase + r;
        if (R < N_NODES) {
          float v = acc[mt][r] + b;
          int ld = last_dst[R];
          int ls = last_src[R];
          int e = (ld >= 0) ? ld : ls;  // dst assignment overwrites src assignment
          if (e >= 0) v = fmaxf(v + fmaf(ea[e], ew, eb), 0.0f);
          ((unsigned short*)outv)[(size_t)R * M + col] = bf16rne(v);
        }
      }
    }
  }
  if (MODE == 1) {
    __syncthreads();
    if (t < 256) {
      float a = red[t] + red[256 + t] + red[512 + t] + red[768 + t];
      float q = red[1024 + t] + red[1280 + t] + red[1536 + t] + red[1792 + t];
      pS1[(size_t)blockIdx.x * 256 + t] = a;
      pS2[(size_t)blockIdx.x * 256 + t] = q;
    }
  }
}

// ------- BN finalize stage 1: 64 blocks reduce 1563 partials -> 64 partials -------
__global__ __launch_bounds__(256) void k_bnred(
    const float* __restrict__ pS1, const float* __restrict__ pS2,
    float* __restrict__ qS1, float* __restrict__ qS2, int nblk) {
  int j = threadIdx.x;  // 256
  int b = blockIdx.x;   // 64
  float s1 = 0.0f, s2 = 0.0f;
  for (int i = b; i < nblk; i += 64) {
    s1 += pS1[(size_t)i * 256 + j];
    s2 += pS2[(size_t)i * 256 + j];
  }
  qS1[b * 256 + j] = s1;
  qS2[b * 256 + j] = s2;
}

// ------- BN finalize stage 2: fold 64 partials, emit scale/shift -------
__global__ __launch_bounds__(256) void k_bnfin2(
    const float* __restrict__ qS1, const float* __restrict__ qS2,
    const float* __restrict__ g, const float* __restrict__ bb,
    float* __restrict__ scale, float* __restrict__ shift) {
  int j = threadIdx.x;  // 256
  float s1 = 0.0f, s2 = 0.0f;
#pragma unroll 8
  for (int i = 0; i < 64; ++i) {
    s1 += qS1[i * 256 + j];
    s2 += qS2[i * 256 + j];
  }
  const float inv = 1.0f / (float)N_NODES;
  float mu = s1 * inv;
  float var = s2 * inv - mu * mu;
  float sc = g[j] * rsqrtf(var + 1e-5f);
  scale[j] = sc;
  shift[j] = fmaf(-mu, sc, bb[j]);
}

extern "C" void kernel_launch(void* const* d_in, const int* in_sizes, int n_in,
                              void* d_out, int out_size, void* d_ws, size_t ws_size,
                              hipStream_t stream) {
  const float* x     = (const float*)d_in[0];
  const int*   ei    = (const int*)d_in[1];
  const float* ea    = (const float*)d_in[2];
  const float* lin_W = (const float*)d_in[3];
  const float* lin_b = (const float*)d_in[4];
  const float* enc_W = (const float*)d_in[5];
  const float* enc_b = (const float*)d_in[6];
  const float* eps   = (const float*)d_in[7];
  const float* e1_W  = (const float*)d_in[8];
  const float* e1_b  = (const float*)d_in[9];
  const float* e2_W  = (const float*)d_in[10];
  const float* e2_b  = (const float*)d_in[11];
  const float* m1_W  = (const float*)d_in[12];
  const float* m1_b  = (const float*)d_in[13];
  const float* bn_g  = (const float*)d_in[14];
  const float* bn_b  = (const float*)d_in[15];
  const float* m2_W  = (const float*)d_in[16];
  const float* m2_b  = (const float*)d_in[17];

  const int NB_SCAN = (N_NODES + 1023) / 1024;  // 98
  const int NB_GEMM = (N_NODES + 63) / 64;      // 1563

  float* ws = (float*)d_ws;
  size_t o = 0;
  unsigned short* hbuf = (unsigned short*)(ws + o); o += (size_t)N_NODES * 64;  // bf16 h
  unsigned* zin_u = (unsigned*)(ws + o);            o += (size_t)N_NODES * 64;  // bf16 zin
  unsigned short* z2_u = (unsigned short*)(ws + o); o += (size_t)N_NODES * 128; // bf16 z2
  int* last_dst = (int*)(ws + o);  o += N_NODES;
  int* last_src = (int*)(ws + o);  o += N_NODES;
  int* deg = (int*)(ws + o);       o += N_NODES;
  int* cnt = (int*)(ws + o);       o += N_NODES;
  int* excl = (int*)(ws + o);      o += N_NODES;
  int* bsum = (int*)(ws + o);      o += 128;
  int* boff = (int*)(ws + o);      o += 128;
  int2* pairE = (int2*)(ws + o);   o += (size_t)E_EDGES * 2;
  unsigned char* posb0 = (unsigned char*)(ws + o); o += (E_EDGES + 3) / 4 + 4;
  unsigned char* posb1 = (unsigned char*)(ws + o); o += (E_EDGES + 3) / 4 + 4;
  float* tabA = ws + o;            o += 2 * 129 * 128;
  float* tabB = ws + o;            o += 2 * 129 * 128;
  float* tsort = ws + o;           o += 2 * 128;
  float* pS1 = ws + o;             o += (size_t)NB_GEMM * 256;
  float* pS2 = ws + o;             o += (size_t)NB_GEMM * 256;
  float* qS1 = ws + o;             o += 64 * 256;
  float* qS2 = ws + o;             o += 64 * 256;
  float* scale = ws + o;           o += 256;
  float* shift = ws + o;           o += 256;
  unsigned short* pk_lin = (unsigned short*)(ws + o); o += 8192;   // 16384 bf16
  unsigned short* pk_m1  = (unsigned short*)(ws + o); o += 32768;  // 2 x 32768 bf16
  unsigned short* pk_m2  = (unsigned short*)(ws + o); o += 32768;  // 2 x 32768 bf16
  if (ws_size < o * sizeof(float)) return;

  hipMemsetAsync(last_dst, 0xFF, 2 * (size_t)N_NODES * sizeof(int), stream);
  hipMemsetAsync(deg, 0, 2 * (size_t)N_NODES * sizeof(int), stream);  // deg + cnt
  k_table<<<2, 128, 0, stream>>>(e1_W, e1_b, e2_W, e2_b, tabA, tabB, tsort);
  k_last<<<(E_EDGES + 255) / 256, 256, 0, stream>>>(ei, last_src, last_dst, deg, E_EDGES);
  k_scan1<<<NB_SCAN, 256, 0, stream>>>(deg, excl, bsum, N_NODES);
  k_scan2<<<1, 128, 0, stream>>>(bsum, boff, NB_SCAN);
  k_scatter<<<(E_EDGES + 255) / 256, 256, 0, stream>>>(ei, ea, excl, boff, cnt, pairE, E_EDGES);
  k_pos<<<(E_EDGES + 255) / 256, 256, 0, stream>>>(pairE, tsort, posb0, posb1, E_EDGES);
  k_pack<<<72, 256, 0, stream>>>(lin_W, m1_W, m2_W, pk_lin, pk_m1, pk_m2);

  // h = x @ lin_W + lin_b, then agg_edge epilogue -> bf16 h
  k_mgemm<128, 128, 0, false, true><<<NB_GEMM, 256, 0, stream>>>(
      x, pk_lin, lin_b, hbuf, nullptr, nullptr, nullptr, nullptr,
      last_dst, last_src, ea, enc_W, enc_b);

  for (int l = 0; l < 2; ++l) {
    k_agg<<<(N_NODES * 64 + 255) / 256, 256, 0, stream>>>(
        hbuf, pairE, l == 0 ? posb0 : posb1, excl, boff,
        tabA + (size_t)l * 129 * 128, tabB + (size_t)l * 129 * 128,
        eps + l, zin_u, N_NODES, E_EDGES);
    k_mgemm<128, 256, 1, false, true><<<NB_GEMM, 256, 0, stream>>>(
        zin_u, pk_m1 + (size_t)l * 32768, m1_b + l * 256, z2_u, nullptr, nullptr,
        pS1, pS2, nullptr, nullptr, nullptr, nullptr, nullptr);
    k_bnred<<<64, 256, 0, stream>>>(pS1, pS2, qS1, qS2, NB_GEMM);
    k_bnfin2<<<1, 256, 0, stream>>>(qS1, qS2, bn_g + l * 256, bn_b + l * 256,
                                    scale, shift);
    if (l == 0) {
      k_mgemm<256, 128, 2, true, true><<<NB_GEMM, 256, 0, stream>>>(
          z2_u, pk_m2, m2_b, hbuf, scale, shift,
          nullptr, nullptr, nullptr, nullptr, nullptr, nullptr, nullptr);
    } else {
      k_mgemm<256, 128, 2, false, false><<<NB_GEMM, 256, 0, stream>>>(
          z2_u, pk_m2 + 32768, m2_b + 128, d_out, scale, shift,
          nullptr, nullptr, nullptr, nullptr, nullptr, nullptr, nullptr);
    }
  }
}

// Round 10
// 630.232 us; speedup vs baseline: 2.7076x; 1.0196x over previous
//
#include <hip/hip_runtime.h>

#define N_NODES 100000
#define E_EDGES 600000
#define HID 128

typedef __attribute__((ext_vector_type(8))) short short8v;
typedef __attribute__((ext_vector_type(4))) float f32x4;

__device__ __forceinline__ unsigned short bf16rne(float x) {
  unsigned u = __float_as_uint(x);
  return (unsigned short)((u + 0x7FFFu + ((u >> 16) & 1u)) >> 16);
}
__device__ __forceinline__ float bf16tof(unsigned short u) {
  return __uint_as_float(((unsigned)u) << 16);
}

// ---- per-node metadata: {last_src, last_dst, deg, cnt} packed in one line ----
__global__ void k_init(int4* __restrict__ meta, int n) {
  int i = blockIdx.x * blockDim.x + threadIdx.x;
  if (i < n) meta[i] = make_int4(-1, -1, 0, 0);
}

__global__ void k_last(const int* __restrict__ ei, int4* __restrict__ meta, int E) {
  int e = blockIdx.x * blockDim.x + threadIdx.x;
  if (e >= E) return;
  int s = ei[e], d = ei[E + e];
  atomicMax(&meta[s].x, e);
  atomicMax(&meta[d].y, e);            // same line as...
  atomicAdd((unsigned*)&meta[d].z, 1u);  // ...this: 2 lines/edge total
}

// ------------- 2-level exclusive scan over deg (CSR row offsets) -------------
__global__ __launch_bounds__(256) void k_scan1(const int4* __restrict__ meta,
                                               int* __restrict__ excl,
                                               int* __restrict__ bsum, int n) {
  __shared__ int sh[256];
  int b = blockIdx.x, t = threadIdx.x;
  int i0 = b * 1024 + t * 4;
  int v0 = (i0 + 0 < n) ? meta[i0 + 0].z : 0;
  int v1 = (i0 + 1 < n) ? meta[i0 + 1].z : 0;
  int v2 = (i0 + 2 < n) ? meta[i0 + 2].z : 0;
  int v3 = (i0 + 3 < n) ? meta[i0 + 3].z : 0;
  int tsum = v0 + v1 + v2 + v3;
  sh[t] = tsum;
  __syncthreads();
  for (int off = 1; off < 256; off <<= 1) {
    int add = (t >= off) ? sh[t - off] : 0;
    __syncthreads();
    sh[t] += add;
    __syncthreads();
  }
  int ex = sh[t] - tsum;
  if (i0 + 0 < n) excl[i0 + 0] = ex;
  if (i0 + 1 < n) excl[i0 + 1] = ex + v0;
  if (i0 + 2 < n) excl[i0 + 2] = ex + v0 + v1;
  if (i0 + 3 < n) excl[i0 + 3] = ex + v0 + v1 + v2;
  if (t == 255) bsum[b] = sh[255];
}

__global__ void k_scan2(const int* __restrict__ bsum, int* __restrict__ boff, int nb) {
  __shared__ int sh[128];
  int t = threadIdx.x;
  int v = (t < nb) ? bsum[t] : 0;
  sh[t] = v;
  __syncthreads();
  for (int off = 1; off < 128; off <<= 1) {
    int add = (t >= off) ? sh[t - off] : 0;
    __syncthreads();
    sh[t] += add;
    __syncthreads();
  }
  if (t < nb) boff[t] = sh[t] - v;
}

// ------- scatter edges into dst buckets: one int2 (src, attr_bits) record -------
__global__ void k_scatter(const int* __restrict__ ei, const float* __restrict__ ea,
                          const int* __restrict__ excl, const int* __restrict__ boff,
                          int4* __restrict__ meta, int2* __restrict__ pairE, int E) {
  int e = blockIdx.x * blockDim.x + threadIdx.x;
  if (e >= E) return;
  int d = ei[E + e];
  int p = excl[d] + boff[d >> 10] + atomicAdd((unsigned*)&meta[d].w, 1u);
  pairE[p] = make_int2(ei[e], __float_as_int(ea[e]));
}

// ---------------- piecewise-linear edge-encoder table (both layers) ----------------
__global__ void k_table(const float* __restrict__ e1_W, const float* __restrict__ e1_b,
                        const float* __restrict__ e2_W, const float* __restrict__ e2_b,
                        float* __restrict__ tabA, float* __restrict__ tabB,
                        float* __restrict__ tsort) {
  const int l = blockIdx.x;  // layer
  const float* W1g = e1_W + l * 128;
  const float* b1g = e1_b + l * 128;
  const float* W2g = e2_W + l * 128 * 128;
  const float* b2g = e2_b + l * 128;
  float* tA = tabA + (size_t)l * 129 * 128;
  float* tB = tabB + (size_t)l * 129 * 128;
  float* tS = tsort + l * 128;
  __shared__ float w1[128], b1[128], key[128];
  __shared__ int idx[128];
  __shared__ float w2[128][128];
  const int t = threadIdx.x;  // 128 threads
  w1[t] = W1g[t];
  b1[t] = b1g[t];
  for (int k = 0; k < 128; ++k) w2[k][t] = W2g[k * 128 + t];
  __syncthreads();
  float s0 = w1[t];
  key[t] = (s0 != 0.0f) ? (-b1[t] / s0) : __builtin_inff();
  idx[t] = t;
  for (int size = 2; size <= 128; size <<= 1) {
    for (int stride = size >> 1; stride > 0; stride >>= 1) {
      __syncthreads();
      int p = t ^ stride;
      if (p > t) {
        bool up = ((t & size) == 0);
        float k1 = key[t], k2 = key[p];
        if (up == (k1 > k2)) {
          int i1 = idx[t], i2 = idx[p];
          key[t] = k2; key[p] = k1; idx[t] = i2; idx[p] = i1;
        }
      }
    }
  }
  __syncthreads();
  tS[t] = key[t];
  float A = 0.0f, B = b2g[t];
  for (int k = 0; k < 128; ++k) {
    float s = w1[k], bb = b1[k], w = w2[k][t];
    if (s < 0.0f) { A = fmaf(s, w, A); B = fmaf(bb, w, B); }
    else if (s == 0.0f && bb > 0.0f) { B = fmaf(bb, w, B); }
  }
  tA[t] = A;
  tB[t] = B;
  for (int i = 0; i < 128; ++i) {
    float kv = key[i];
    int kk = idx[i];
    if (kv < __builtin_inff()) {
      float s = w1[kk], bb = b1[kk], w = w2[kk][t];
      if (s > 0.0f) { A = fmaf(s, w, A); B = fmaf(bb, w, B); }
      else { A = fmaf(-s, w, A); B = fmaf(-bb, w, B); }
    }
    tA[(i + 1) * 128 + t] = A;
    tB[(i + 1) * 128 + t] = B;
  }
}

// ---- per-edge interval indices for BOTH layers in one pass over bucket order ----
__global__ __launch_bounds__(256) void k_pos(const int2* __restrict__ pairE,
                                             const float* __restrict__ tsort,
                                             unsigned char* __restrict__ posb0,
                                             unsigned char* __restrict__ posb1, int E) {
  __shared__ float ts0[128], ts1[128];
  if (threadIdx.x < 128) {
    ts0[threadIdx.x] = tsort[threadIdx.x];
    ts1[threadIdx.x] = tsort[128 + threadIdx.x];
  }
  __syncthreads();
  int i = blockIdx.x * blockDim.x + threadIdx.x;
  if (i >= E) return;
  float a = __int_as_float(pairE[i].y);
  int p0 = 0, p1 = 0;
#pragma unroll
  for (int st = 64; st > 0; st >>= 1) {
    if (p0 + st <= 128 && ts0[p0 + st - 1] < a) p0 += st;
    if (p1 + st <= 128 && ts1[p1 + st - 1] < a) p1 += st;
  }
  posb0[i] = (unsigned char)p0;
  posb1[i] = (unsigned char)p1;
}

// -- per-node gather-aggregate (bf16 h): zin[n] = bf16((1+eps)*h[n] + sum relu) --
__global__ __launch_bounds__(256) void k_agg(
    const unsigned short* __restrict__ h, const int2* __restrict__ pairE,
    const unsigned char* __restrict__ posb, const int* __restrict__ excl,
    const int* __restrict__ boff, const float* __restrict__ tabA,
    const float* __restrict__ tabB, const float* __restrict__ epsP,
    unsigned* __restrict__ zin, int N, int E) {
  // wave-uniform node index (forces scalar bucket bounds + s_load of edge data)
  int w = __builtin_amdgcn_readfirstlane((int)((blockIdx.x * 256 + threadIdx.x) >> 6));
  if (w >= N) return;
  int lane = threadIdx.x & 63;
  int start = excl[w] + boff[w >> 10];
  int end = (w + 1 < N) ? (excl[w + 1] + boff[(w + 1) >> 10]) : E;
  int j = lane * 2;
  float a0 = 0.0f, a1 = 0.0f, c0 = 0.0f, c1 = 0.0f;
  int i = start;
  for (; i + 2 <= end; i += 2) {
    int2 pr0 = pairE[i], pr1 = pairE[i + 1];
    int p0 = posb[i], p1 = posb[i + 1];
    float aa = __int_as_float(pr0.y), ab = __int_as_float(pr1.y);
    unsigned hv0 = *(const unsigned*)(h + (size_t)pr0.x * HID + j);
    float2 A0 = *(const float2*)(tabA + (size_t)p0 * HID + j);
    float2 B0 = *(const float2*)(tabB + (size_t)p0 * HID + j);
    unsigned hv1 = *(const unsigned*)(h + (size_t)pr1.x * HID + j);
    float2 A1 = *(const float2*)(tabA + (size_t)p1 * HID + j);
    float2 B1 = *(const float2*)(tabB + (size_t)p1 * HID + j);
    a0 += fmaxf(__uint_as_float(hv0 << 16) + fmaf(A0.x, aa, B0.x), 0.0f);
    a1 += fmaxf(__uint_as_float(hv0 & 0xFFFF0000u) + fmaf(A0.y, aa, B0.y), 0.0f);
    c0 += fmaxf(__uint_as_float(hv1 << 16) + fmaf(A1.x, ab, B1.x), 0.0f);
    c1 += fmaxf(__uint_as_float(hv1 & 0xFFFF0000u) + fmaf(A1.y, ab, B1.y), 0.0f);
  }
  if (i < end) {
    int2 pr0 = pairE[i];
    int p0 = posb[i];
    float aa = __int_as_float(pr0.y);
    unsigned hv0 = *(const unsigned*)(h + (size_t)pr0.x * HID + j);
    float2 A0 = *(const float2*)(tabA + (size_t)p0 * HID + j);
    float2 B0 = *(const float2*)(tabB + (size_t)p0 * HID + j);
    a0 += fmaxf(__uint_as_float(hv0 << 16) + fmaf(A0.x, aa, B0.x), 0.0f);
    a1 += fmaxf(__uint_as_float(hv0 & 0xFFFF0000u) + fmaf(A0.y, aa, B0.y), 0.0f);
  }
  a0 += c0;
  a1 += c1;
  float ep1 = 1.0f + *epsP;
  unsigned hn = *(const unsigned*)(h + (size_t)w * HID + j);
  float ox = fmaf(ep1, __uint_as_float(hn << 16), a0);
  float oy = fmaf(ep1, __uint_as_float(hn & 0xFFFF0000u), a1);
  zin[(size_t)w * 64 + lane] = (unsigned)bf16rne(ox) | ((unsigned)bf16rne(oy) << 16);
}

// ------------- weight pack into B-fragment layout (bf16) -------------
__device__ __forceinline__ void pack_one(const float* __restrict__ W, int K, int M,
                                         int t, unsigned short* __restrict__ out) {
  int lane = t & 63, f = t >> 6;
  int KS = K >> 5;
  int mt = f / KS, ks = f - mt * KS;
  int col = mt * 16 + (lane & 15);
  int kb = ks * 32 + ((lane >> 4) * 8);
  unsigned r0, r1, r2, r3;
  r0 = bf16rne(W[(size_t)(kb + 0) * M + col]) | ((unsigned)bf16rne(W[(size_t)(kb + 1) * M + col]) << 16);
  r1 = bf16rne(W[(size_t)(kb + 2) * M + col]) | ((unsigned)bf16rne(W[(size_t)(kb + 3) * M + col]) << 16);
  r2 = bf16rne(W[(size_t)(kb + 4) * M + col]) | ((unsigned)bf16rne(W[(size_t)(kb + 5) * M + col]) << 16);
  r3 = bf16rne(W[(size_t)(kb + 6) * M + col]) | ((unsigned)bf16rne(W[(size_t)(kb + 7) * M + col]) << 16);
  uint4 v = make_uint4(r0, r1, r2, r3);
  *(uint4*)(out + ((size_t)f * 64 + lane) * 8) = v;
}

__global__ __launch_bounds__(256) void k_pack(
    const float* __restrict__ lin_W, const float* __restrict__ m1_W,
    const float* __restrict__ m2_W, unsigned short* __restrict__ pk_lin,
    unsigned short* __restrict__ pk_m1, unsigned short* __restrict__ pk_m2) {
  int t = blockIdx.x * 256 + threadIdx.x;
  if (t < 2048) {
    pack_one(lin_W, 128, 128, t, pk_lin);
  } else if (t < 10240) {
    int u = t - 2048;
    int l = u >> 12;
    pack_one(m1_W + (size_t)l * 128 * 256, 128, 256, u & 4095, pk_m1 + (size_t)l * 32768);
  } else if (t < 18432) {
    int u = t - 10240;
    int l = u >> 12;
    pack_one(m2_W + (size_t)l * 256 * 128, 256, 128, u & 4095, pk_m2 + (size_t)l * 32768);
  }
}

// ---------------- MFMA skinny GEMM with LDS-staged B-panel ----------------
// MODE 0: in fp32 x; epilogue agg_edge(meta, enc) -> bf16 h
// MODE 1: in bf16 zin (direct A-frags); out bf16 z2 + BN partials (LDS reduce)
// MODE 2: in bf16 z2, pre-op relu(z*scale+shift); out bf16 h (OBF) or fp32 d_out
template <int K, int M, int MODE, bool RELU_OUT, bool OBF>
__global__ __launch_bounds__(256) void k_mgemm(
    const void* __restrict__ in0, const unsigned short* __restrict__ pkW,
    const float* __restrict__ bias, void* __restrict__ outv,
    const float* __restrict__ pre_a, const float* __restrict__ pre_b,
    float* __restrict__ pS1, float* __restrict__ pS2,
    const int4* __restrict__ meta, const float* __restrict__ ea,
    const float* __restrict__ encW, const float* __restrict__ encb) {
  constexpr int KS = K / 32, MT = M / 16;
  constexpr int NFRAG = MT * KS;                 // 1 KB per fragment
  __shared__ unsigned short bsh[NFRAG * 512];    // 32-64 KB B panel
  __shared__ float red[(MODE == 1) ? 2048 : 1];  // [2][4 waves][256 cols]
  const int t = threadIdx.x;
  const int w = t >> 6, lane = t & 63;
  const int row0 = blockIdx.x * 64 + w * 16;
  const int arow = row0 + (lane & 15);
  const int rg = arow < N_NODES ? arow : N_NODES - 1;
  const int kb = (lane >> 4) * 8;

  // cooperative B-panel stage: global (L2) -> LDS, once per block
  {
    const uint4* gp = (const uint4*)pkW;
    uint4* lp = (uint4*)bsh;
#pragma unroll
    for (int c = 0; c < NFRAG / 4; ++c) {
      int idx = c * 256 + t;
      lp[idx] = gp[idx];
    }
  }

  short8v afrag[KS];
#pragma unroll
  for (int ks = 0; ks < KS; ++ks) {
    const int k0 = ks * 32 + kb;
    if (MODE == 0) {
      const float* in = (const float*)in0;
      float4 v0 = *(const float4*)(in + (size_t)rg * K + k0);
      float4 v1 = *(const float4*)(in + (size_t)rg * K + k0 + 4);
      short8v a;
      a[0] = (short)bf16rne(v0.x); a[1] = (short)bf16rne(v0.y);
      a[2] = (short)bf16rne(v0.z); a[3] = (short)bf16rne(v0.w);
      a[4] = (short)bf16rne(v1.x); a[5] = (short)bf16rne(v1.y);
      a[6] = (short)bf16rne(v1.z); a[7] = (short)bf16rne(v1.w);
      afrag[ks] = a;
    } else if (MODE == 1) {
      afrag[ks] = *(const short8v*)((const unsigned short*)in0 + (size_t)rg * K + k0);
    } else {
      short8v raw = *(const short8v*)((const unsigned short*)in0 + (size_t)rg * K + k0);
      float4 sa0 = *(const float4*)(pre_a + k0);
      float4 sa1 = *(const float4*)(pre_a + k0 + 4);
      float4 sb0 = *(const float4*)(pre_b + k0);
      float4 sb1 = *(const float4*)(pre_b + k0 + 4);
      short8v a;
      a[0] = (short)bf16rne(fmaxf(fmaf(bf16tof((unsigned short)raw[0]), sa0.x, sb0.x), 0.0f));
      a[1] = (short)bf16rne(fmaxf(fmaf(bf16tof((unsigned short)raw[1]), sa0.y, sb0.y), 0.0f));
      a[2] = (short)bf16rne(fmaxf(fmaf(bf16tof((unsigned short)raw[2]), sa0.z, sb0.z), 0.0f));
      a[3] = (short)bf16rne(fmaxf(fmaf(bf16tof((unsigned short)raw[3]), sa0.w, sb0.w), 0.0f));
      a[4] = (short)bf16rne(fmaxf(fmaf(bf16tof((unsigned short)raw[4]), sa1.x, sb1.x), 0.0f));
      a[5] = (short)bf16rne(fmaxf(fmaf(bf16tof((unsigned short)raw[5]), sa1.y, sb1.y), 0.0f));
      a[6] = (short)bf16rne(fmaxf(fmaf(bf16tof((unsigned short)raw[6]), sa1.z, sb1.z), 0.0f));
      a[7] = (short)bf16rne(fmaxf(fmaf(bf16tof((unsigned short)raw[7]), sa1.w, sb1.w), 0.0f));
      afrag[ks] = a;
    }
  }
  __syncthreads();  // B panel resident

  f32x4 acc[MT];
#pragma unroll
  for (int mt = 0; mt < MT; ++mt) acc[mt] = (f32x4){0.f, 0.f, 0.f, 0.f};
#pragma unroll
  for (int mt = 0; mt < MT; ++mt) {
#pragma unroll
    for (int ks = 0; ks < KS; ++ks) {
      short8v bfrag = *(const short8v*)&bsh[(mt * KS + ks) * 512 + lane * 8];
      acc[mt] = __builtin_amdgcn_mfma_f32_16x16x32_bf16(afrag[ks], bfrag, acc[mt], 0, 0, 0);
    }
  }

  // epilogue: C/D layout col = lane&15, row = (lane>>4)*4 + reg
  const int colb = lane & 15;
  const int rbase = row0 + (lane >> 4) * 4;
  int esel[4];
  float eav[4];
  if (MODE == 0) {
#pragma unroll
    for (int r = 0; r < 4; ++r) {
      int R = rbase + r;
      int4 m = (R < N_NODES) ? meta[R] : make_int4(-1, -1, 0, 0);
      int e = (m.y >= 0) ? m.y : m.x;  // dst assignment overwrites src assignment
      esel[r] = e;
      eav[r] = (e >= 0) ? ea[e] : 0.0f;
    }
  }
#pragma unroll
  for (int mt = 0; mt < MT; ++mt) {
    const int col = mt * 16 + colb;
    const float b = bias[col];
    if (MODE == 1) {
      unsigned short* out = (unsigned short*)outv;
      float s1 = 0.0f, s2 = 0.0f;
#pragma unroll
      for (int r = 0; r < 4; ++r) {
        int R = rbase + r;
        if (R < N_NODES) {
          float v = acc[mt][r] + b;
          out[(size_t)R * M + col] = bf16rne(v);
          s1 += v;
          s2 = fmaf(v, v, s2);
        }
      }
      s1 += __shfl_xor(s1, 16);
      s1 += __shfl_xor(s1, 32);
      s2 += __shfl_xor(s2, 16);
      s2 += __shfl_xor(s2, 32);
      if (lane < 16) {
        red[w * 256 + col] = s1;
        red[1024 + w * 256 + col] = s2;
      }
    } else if (MODE == 2) {
#pragma unroll
      for (int r = 0; r < 4; ++r) {
        int R = rbase + r;
        if (R < N_NODES) {
          float v = acc[mt][r] + b;
          if (RELU_OUT) v = fmaxf(v, 0.0f);
          if (OBF) ((unsigned short*)outv)[(size_t)R * M + col] = bf16rne(v);
          else ((float*)outv)[(size_t)R * M + col] = v;
        }
      }
    } else {
      const float ew = encW[col], eb = encb[col];
#pragma unroll
      for (int r = 0; r < 4; ++r) {
        int R = rbase + r;
        if (R < N_NODES) {
          float v = acc[mt][r] + b;
          if (esel[r] >= 0) v = fmaxf(v + fmaf(eav[r], ew, eb), 0.0f);
          ((unsigned short*)outv)[(size_t)R * M + col] = bf16rne(v);
        }
      }
    }
  }
  if (MODE == 1) {
    __syncthreads();
    if (t < 256) {
      float a = red[t] + red[256 + t] + red[512 + t] + red[768 + t];
      float q = red[1024 + t] + red[1280 + t] + red[1536 + t] + red[1792 + t];
      pS1[(size_t)blockIdx.x * 256 + t] = a;
      pS2[(size_t)blockIdx.x * 256 + t] = q;
    }
  }
}

// ------- BN finalize stage 1: 64 blocks reduce 1563 partials -> 64 partials -------
__global__ __launch_bounds__(256) void k_bnred(
    const float* __restrict__ pS1, const float* __restrict__ pS2,
    float* __restrict__ qS1, float* __restrict__ qS2, int nblk) {
  int j = threadIdx.x;  // 256
  int b = blockIdx.x;   // 64
  float s1 = 0.0f, s2 = 0.0f;
  for (int i = b; i < nblk; i += 64) {
    s1 += pS1[(size_t)i * 256 + j];
    s2 += pS2[(size_t)i * 256 + j];
  }
  qS1[b * 256 + j] = s1;
  qS2[b * 256 + j] = s2;
}

// ------- BN finalize stage 2: fold 64 partials, emit scale/shift -------
__global__ __launch_bounds__(256) void k_bnfin2(
    const float* __restrict__ qS1, const float* __restrict__ qS2,
    const float* __restrict__ g, const float* __restrict__ bb,
    float* __restrict__ scale, float* __restrict__ shift) {
  int j = threadIdx.x;  // 256
  float s1 = 0.0f, s2 = 0.0f;
#pragma unroll 8
  for (int i = 0; i < 64; ++i) {
    s1 += qS1[i * 256 + j];
    s2 += qS2[i * 256 + j];
  }
  const float inv = 1.0f / (float)N_NODES;
  float mu = s1 * inv;
  float var = s2 * inv - mu * mu;
  float sc = g[j] * rsqrtf(var + 1e-5f);
  scale[j] = sc;
  shift[j] = fmaf(-mu, sc, bb[j]);
}

extern "C" void kernel_launch(void* const* d_in, const int* in_sizes, int n_in,
                              void* d_out, int out_size, void* d_ws, size_t ws_size,
                              hipStream_t stream) {
  const float* x     = (const float*)d_in[0];
  const int*   ei    = (const int*)d_in[1];
  const float* ea    = (const float*)d_in[2];
  const float* lin_W = (const float*)d_in[3];
  const float* lin_b = (const float*)d_in[4];
  const float* enc_W = (const float*)d_in[5];
  const float* enc_b = (const float*)d_in[6];
  const float* eps   = (const float*)d_in[7];
  const float* e1_W  = (const float*)d_in[8];
  const float* e1_b  = (const float*)d_in[9];
  const float* e2_W  = (const float*)d_in[10];
  const float* e2_b  = (const float*)d_in[11];
  const float* m1_W  = (const float*)d_in[12];
  const float* m1_b  = (const float*)d_in[13];
  const float* bn_g  = (const float*)d_in[14];
  const float* bn_b  = (const float*)d_in[15];
  const float* m2_W  = (const float*)d_in[16];
  const float* m2_b  = (const float*)d_in[17];

  const int NB_SCAN = (N_NODES + 1023) / 1024;  // 98
  const int NB_GEMM = (N_NODES + 63) / 64;      // 1563

  float* ws = (float*)d_ws;
  size_t o = 0;
  unsigned short* hbuf = (unsigned short*)(ws + o); o += (size_t)N_NODES * 64;  // bf16 h
  unsigned* zin_u = (unsigned*)(ws + o);            o += (size_t)N_NODES * 64;  // bf16 zin
  unsigned short* z2_u = (unsigned short*)(ws + o); o += (size_t)N_NODES * 128; // bf16 z2
  int4* meta = (int4*)(ws + o);    o += (size_t)N_NODES * 4;
  int* excl = (int*)(ws + o);      o += N_NODES;
  int* bsum = (int*)(ws + o);      o += 128;
  int* boff = (int*)(ws + o);      o += 128;
  int2* pairE = (int2*)(ws + o);   o += (size_t)E_EDGES * 2;
  unsigned char* posb0 = (unsigned char*)(ws + o); o += (E_EDGES + 3) / 4 + 4;
  unsigned char* posb1 = (unsigned char*)(ws + o); o += (E_EDGES + 3) / 4 + 4;
  float* tabA = ws + o;            o += 2 * 129 * 128;
  float* tabB = ws + o;            o += 2 * 129 * 128;
  float* tsort = ws + o;           o += 2 * 128;
  float* pS1 = ws + o;             o += (size_t)NB_GEMM * 256;
  float* pS2 = ws + o;             o += (size_t)NB_GEMM * 256;
  float* qS1 = ws + o;             o += 64 * 256;
  float* qS2 = ws + o;             o += 64 * 256;
  float* scale = ws + o;           o += 256;
  float* shift = ws + o;           o += 256;
  unsigned short* pk_lin = (unsigned short*)(ws + o); o += 8192;   // 16384 bf16
  unsigned short* pk_m1  = (unsigned short*)(ws + o); o += 32768;  // 2 x 32768 bf16
  unsigned short* pk_m2  = (unsigned short*)(ws + o); o += 32768;  // 2 x 32768 bf16
  if (ws_size < o * sizeof(float)) return;

  k_init<<<(N_NODES + 255) / 256, 256, 0, stream>>>(meta, N_NODES);
  k_table<<<2, 128, 0, stream>>>(e1_W, e1_b, e2_W, e2_b, tabA, tabB, tsort);
  k_last<<<(E_EDGES + 255) / 256, 256, 0, stream>>>(ei, meta, E_EDGES);
  k_scan1<<<NB_SCAN, 256, 0, stream>>>(meta, excl, bsum, N_NODES);
  k_scan2<<<1, 128, 0, stream>>>(bsum, boff, NB_SCAN);
  k_scatter<<<(E_EDGES + 255) / 256, 256, 0, stream>>>(ei, ea, excl, boff, meta, pairE, E_EDGES);
  k_pos<<<(E_EDGES + 255) / 256, 256, 0, stream>>>(pairE, tsort, posb0, posb1, E_EDGES);
  k_pack<<<72, 256, 0, stream>>>(lin_W, m1_W, m2_W, pk_lin, pk_m1, pk_m2);

  // h = x @ lin_W + lin_b, then agg_edge epilogue -> bf16 h
  k_mgemm<128, 128, 0, false, true><<<NB_GEMM, 256, 0, stream>>>(
      x, pk_lin, lin_b, hbuf, nullptr, nullptr, nullptr, nullptr,
      meta, ea, enc_W, enc_b);

  for (int l = 0; l < 2; ++l) {
    k_agg<<<(N_NODES * 64 + 255) / 256, 256, 0, stream>>>(
        hbuf, pairE, l == 0 ? posb0 : posb1, excl, boff,
        tabA + (size_t)l * 129 * 128, tabB + (size_t)l * 129 * 128,
        eps + l, zin_u, N_NODES, E_EDGES);
    k_mgemm<128, 256, 1, false, true><<<NB_GEMM, 256, 0, stream>>>(
        zin_u, pk_m1 + (size_t)l * 32768, m1_b + l * 256, z2_u, nullptr, nullptr,
        pS1, pS2, nullptr, nullptr, nullptr, nullptr);
    k_bnred<<<64, 256, 0, stream>>>(pS1, pS2, qS1, qS2, NB_GEMM);
    k_bnfin2<<<1, 256, 0, stream>>>(qS1, qS2, bn_g + l * 256, bn_b + l * 256,
                                    scale, shift);
    if (l == 0) {
      k_mgemm<256, 128, 2, true, true><<<NB_GEMM, 256, 0, stream>>>(
          z2_u, pk_m2, m2_b, hbuf, scale, shift,
          nullptr, nullptr, nullptr, nullptr, nullptr, nullptr);
    } else {
      k_mgemm<256, 128, 2, false, false><<<NB_GEMM, 256, 0, stream>>>(
          z2_u, pk_m2 + 32768, m2_b + 128, d_out, scale, shift,
          nullptr, nullptr, nullptr, nullptr, nullptr, nullptr);
    }
  }
}